// Round 3
// baseline (390.470 us; speedup 1.0000x reference)
//
#include <hip/hip_runtime.h>
#include <hip/hip_bf16.h>
#include <hip/hip_fp16.h>

// ---------------------------------------------------------------------------
// 2-layer GAT, N=50000, E=1.6M (+N self loops).
// CSR build (counting sort) -> GEMM1 [fp16 MFMA, fused alpha] -> agg1(fp16 out)
//  -> GEMM2 [fp16 MFMA, fused alpha] -> agg2 -> d_out.
// Softmax computed without max-shift (shift-invariant; |e| ~ 1.5).
// R2: hierarchical scan. R3: col[] uint16. R4: fp16 gather payload.
// R6: counting-sort CSR build. R9: MFMA GEMMs (v_mfma_f32_16x16x32_f16).
// R10/R11: wide-lane gather layouts + 12-edge SW pipeline (latency probe:
//      only +7% => agg1 is L2-miss-traffic-bound, 171MB @ 3.2TB/s).
// R12: agg1 XCD channel-slicing — slice = blockIdx.x % 8 pins a 16-channel
//      slice (50000 x 32B = 1.6MB) to one XCD's L2. Per-XCD footprint drops
//      12.8MB -> 1.6MB (L2-resident). col[] read directly per lane (no shfl).
//      Expected agg1 FETCH 171MB -> ~50MB.
// ---------------------------------------------------------------------------

#define LRELU_SLOPE 0.2f
#define NBMAX 200        // max dst buckets (N <= 51200)
#define NBLK  512        // blocks in hist/scatter passes
#define BCAP  16384      // per-bucket record capacity (mean ~8163)
#define CAPIMG 16384     // csr_scatter LDS image entries

typedef _Float16 f16x8 __attribute__((ext_vector_type(8)));
typedef _Float16 f16x4 __attribute__((ext_vector_type(4)));
typedef float f32x4 __attribute__((ext_vector_type(4)));

// ---------------- CSR build ----------------

__global__ __launch_bounds__(256) void hist_kernel(const int* __restrict__ ei_dst,
                                                   int* __restrict__ hist, int E, int chunk) {
    __shared__ int h[NBMAX];
    int t = threadIdx.x;
    for (int i = t; i < NBMAX; i += 256) h[i] = 0;
    __syncthreads();
    int begin = blockIdx.x * chunk;
    int endE = min(E, begin + chunk);
    for (int e = begin + t; e < endE; e += 256) atomicAdd(&h[ei_dst[e] >> 8], 1);
    __syncthreads();
    for (int i = t; i < NBMAX; i += 256) hist[i * NBLK + blockIdx.x] = h[i];
}

__global__ __launch_bounds__(512) void bucket_scan_kernel(int* __restrict__ hist,
                                                          int* __restrict__ gfill) {
    __shared__ int buf[2][NBLK];
    int b = blockIdx.x, t = threadIdx.x;
    buf[0][t] = hist[b * NBLK + t];
    __syncthreads();
    int pi = 0;
#pragma unroll
    for (int off = 1; off < NBLK; off <<= 1) {
        int v = buf[pi][t];
        if (t >= off) v += buf[pi][t - off];
        buf[pi ^ 1][t] = v;
        __syncthreads();
        pi ^= 1;
    }
    hist[b * NBLK + t] = (t == 0) ? 0 : buf[pi][t - 1];
    if (t == 0) gfill[b] = buf[pi][NBLK - 1];
}

__global__ __launch_bounds__(256) void scatter2_kernel(const int* __restrict__ ei_src,
                                                       const int* __restrict__ ei_dst,
                                                       const int* __restrict__ hist,
                                                       unsigned int* __restrict__ records,
                                                       int E, int chunk) {
    __shared__ int base[NBMAX];
    __shared__ int lcnt[NBMAX];
    int t = threadIdx.x;
    for (int i = t; i < NBMAX; i += 256) {
        base[i] = hist[i * NBLK + blockIdx.x];
        lcnt[i] = 0;
    }
    __syncthreads();
    int begin = blockIdx.x * chunk;
    int endE = min(E, begin + chunk);
    for (int e = begin + t; e < endE; e += 256) {
        int s = ei_src[e], d = ei_dst[e];
        int bkt = d >> 8;
        unsigned int rec = (unsigned int)d | ((unsigned int)s << 16);
        int r = atomicAdd(&lcnt[bkt], 1);
        records[(size_t)bkt * BCAP + base[bkt] + r] = rec;
    }
}

__global__ __launch_bounds__(256) void deg_kernel(const unsigned int* __restrict__ records,
                                                  const int* __restrict__ gfill,
                                                  int* __restrict__ deg, int N) {
    __shared__ int cnt[256];
    int t = threadIdx.x, b = blockIdx.x;
    cnt[t] = 1;
    __syncthreads();
    int c = gfill[b];
    const unsigned int* r = records + (size_t)b * BCAP;
    for (int i = t; i < c; i += 256) atomicAdd(&cnt[r[i] & 255], 1);
    __syncthreads();
    int gi = (b << 8) + t;
    if (gi < N) deg[gi] = cnt[t];
}

__global__ __launch_bounds__(256) void scan_blocksums_kernel(const int* __restrict__ gfill,
                                                             int* __restrict__ bsums,
                                                             int* __restrict__ row_ptr,
                                                             int nblocks, int n, int total) {
    __shared__ int buf[2][256];
    int t = threadIdx.x;
    int v0 = 0;
    if (t < nblocks) v0 = gfill[t] + min(256, n - (t << 8));
    buf[0][t] = v0;
    __syncthreads();
    int pi = 0;
#pragma unroll
    for (int off = 1; off < 256; off <<= 1) {
        int v = buf[pi][t];
        if (t >= off) v += buf[pi][t - off];
        buf[pi ^ 1][t] = v;
        __syncthreads();
        pi ^= 1;
    }
    if (t < nblocks) bsums[t] = (t == 0) ? 0 : buf[pi][t - 1];
    if (t == 0) row_ptr[n] = total;
}

__global__ __launch_bounds__(256) void scan_down_kernel(const int* __restrict__ deg,
                                                        const int* __restrict__ blockSums,
                                                        int* __restrict__ row_ptr, int n) {
    __shared__ int buf[2][256];
    int t = threadIdx.x;
    int i = blockIdx.x * 256 + t;
    int d = (i < n) ? deg[i] : 0;
    buf[0][t] = d;
    __syncthreads();
    int pi = 0;
#pragma unroll
    for (int off = 1; off < 256; off <<= 1) {
        int v = buf[pi][t];
        if (t >= off) v += buf[pi][t - off];
        buf[pi ^ 1][t] = v;
        __syncthreads();
        pi ^= 1;
    }
    if (i < n) row_ptr[i] = blockSums[blockIdx.x] + buf[pi][t] - d;
}

__global__ __launch_bounds__(256) void csr_scatter_kernel(const unsigned int* __restrict__ records,
                                                          const int* __restrict__ gfill,
                                                          const int* __restrict__ row_ptr,
                                                          unsigned short* __restrict__ col,
                                                          int N) {
    __shared__ unsigned short img[CAPIMG];
    __shared__ int lfill[256];
    int t = threadIdx.x, b = blockIdx.x;
    int bBase = b << 8;
    int bEnd = min(bBase + 256, N);
    int rbase = row_ptr[bBase];
    int size = row_ptr[bEnd] - rbase;
    bool lds = (size <= CAPIMG);
    int gi = bBase + t;
    if (gi < bEnd) {
        int rp = row_ptr[gi];
        int local = rp - rbase;
        lfill[t] = local + 1;  // slot 0 = self loop
        if (lds) img[local] = (unsigned short)gi;
        else col[rp] = (unsigned short)gi;
    }
    __syncthreads();
    int c = gfill[b];
    const unsigned int* r = records + (size_t)b * BCAP;
    for (int i = t; i < c; i += 256) {
        unsigned int rec = r[i];
        int d8 = rec & 255;
        unsigned short s = (unsigned short)(rec >> 16);
        int p = atomicAdd(&lfill[d8], 1);
        if (lds) img[p] = s;
        else col[rbase + p] = s;
    }
    __syncthreads();
    if (lds) {
        for (int i = t; i < size; i += 256) col[rbase + i] = img[i];
    }
}

// ---------------- GEMM1: X fp32 [n,128] @ W1 [128,128] -> h1h fp16 + alphas ----
// Per block: 64 rows (4 waves x 16). MFMA 16x16x32 f16; W^T staged fp16 LDS.

__global__ __launch_bounds__(256) void gemm1_mfma_kernel(const float* __restrict__ X,
                                                         const float* __restrict__ W,
                                                         __half* __restrict__ outh,
                                                         const float* __restrict__ a_src,
                                                         const float* __restrict__ a_dst,
                                                         float* __restrict__ as_out,
                                                         float* __restrict__ ad_out, int nrows) {
    constexpr int KP = 136;  // padded k-stride in halves
    __shared__ _Float16 wlds[128 * KP];  // wlds[n][k] = W[k][n]
    int t = threadIdx.x;
    int wv = t >> 6, lane = t & 63;
    int quad = lane >> 4, m16 = lane & 15;
    // stage W^T as fp16
    for (int i = t; i < 4096; i += 256) {  // 128*128/4
        int k = i >> 5;
        int n0 = (i & 31) << 2;
        float4 v = *(const float4*)(W + k * 128 + n0);
        wlds[(n0 + 0) * KP + k] = (_Float16)v.x;
        wlds[(n0 + 1) * KP + k] = (_Float16)v.y;
        wlds[(n0 + 2) * KP + k] = (_Float16)v.z;
        wlds[(n0 + 3) * KP + k] = (_Float16)v.w;
    }
    __syncthreads();

    int row = blockIdx.x * 64 + wv * 16 + m16;
    int rowC = min(row, nrows - 1);
    const float* xp = X + (size_t)rowC * 128;

    f32x4 acc[8];
#pragma unroll
    for (int nt = 0; nt < 8; ++nt) acc[nt] = (f32x4)0.f;

    for (int kt = 0; kt < 128; kt += 32) {
        float4 v0 = *(const float4*)(xp + kt + quad * 8);
        float4 v1 = *(const float4*)(xp + kt + quad * 8 + 4);
        f16x8 af;
        af[0] = (_Float16)v0.x; af[1] = (_Float16)v0.y;
        af[2] = (_Float16)v0.z; af[3] = (_Float16)v0.w;
        af[4] = (_Float16)v1.x; af[5] = (_Float16)v1.y;
        af[6] = (_Float16)v1.z; af[7] = (_Float16)v1.w;
#pragma unroll
        for (int nt = 0; nt < 8; ++nt) {
            f16x8 bf = *(const f16x8*)(&wlds[(nt * 16 + m16) * KP + kt + quad * 8]);
            acc[nt] = __builtin_amdgcn_mfma_f32_16x16x32_f16(af, bf, acc[nt], 0, 0, 0);
        }
    }

    // per-lane alpha coefficients for its column in each tile
    float aS[8], aD[8];
#pragma unroll
    for (int nt = 0; nt < 8; ++nt) {
        aS[nt] = a_src[nt * 16 + m16];
        aD[nt] = a_dst[nt * 16 + m16];
    }
    int rowBaseW = blockIdx.x * 64 + wv * 16;
#pragma unroll
    for (int r = 0; r < 4; ++r) {
        int orow = rowBaseW + quad * 4 + r;
        bool ov = orow < nrows;
        // fp16 store of C row segment
        if (ov) {
#pragma unroll
            for (int nt = 0; nt < 8; ++nt)
                outh[(size_t)orow * 128 + nt * 16 + m16] = __float2half(acc[nt][r]);
        }
        // alpha: per head h, reduce cols (2 tiles x 16 lanes)
#pragma unroll
        for (int h = 0; h < 4; ++h) {
            float ss = acc[2 * h][r] * aS[2 * h] + acc[2 * h + 1][r] * aS[2 * h + 1];
            float dd = acc[2 * h][r] * aD[2 * h] + acc[2 * h + 1][r] * aD[2 * h + 1];
#pragma unroll
            for (int o = 1; o < 16; o <<= 1) {
                ss += __shfl_xor(ss, o, 64);
                dd += __shfl_xor(dd, o, 64);
            }
            if (ov && m16 == h) {
                as_out[orow * 4 + h] = ss;
                ad_out[orow * 4 + h] = dd;
            }
        }
    }
}

// ---------------- GEMM2: h2in fp16 [n,128] @ W2 [128,64] -> h2bh fp16 + alphas --

__global__ __launch_bounds__(256) void gemm2_mfma_kernel(const __half* __restrict__ Xh,
                                                         const float* __restrict__ W,
                                                         __half* __restrict__ outh,
                                                         const float* __restrict__ a_src,
                                                         const float* __restrict__ a_dst,
                                                         float* __restrict__ as_out,
                                                         float* __restrict__ ad_out, int nrows) {
    constexpr int KP = 136;
    __shared__ _Float16 wlds[64 * KP];  // wlds[n][k] = W[k][n]
    int t = threadIdx.x;
    int wv = t >> 6, lane = t & 63;
    int quad = lane >> 4, m16 = lane & 15;
    for (int i = t; i < 2048; i += 256) {  // 128*64/4
        int k = i >> 4;
        int n0 = (i & 15) << 2;
        float4 v = *(const float4*)(W + k * 64 + n0);
        wlds[(n0 + 0) * KP + k] = (_Float16)v.x;
        wlds[(n0 + 1) * KP + k] = (_Float16)v.y;
        wlds[(n0 + 2) * KP + k] = (_Float16)v.z;
        wlds[(n0 + 3) * KP + k] = (_Float16)v.w;
    }
    __syncthreads();

    int row = blockIdx.x * 64 + wv * 16 + m16;
    int rowC = min(row, nrows - 1);
    const _Float16* xp = (const _Float16*)Xh + (size_t)rowC * 128;

    f32x4 acc[4];
#pragma unroll
    for (int nt = 0; nt < 4; ++nt) acc[nt] = (f32x4)0.f;

    for (int kt = 0; kt < 128; kt += 32) {
        f16x8 af = *(const f16x8*)(xp + kt + quad * 8);
#pragma unroll
        for (int nt = 0; nt < 4; ++nt) {
            f16x8 bf = *(const f16x8*)(&wlds[(nt * 16 + m16) * KP + kt + quad * 8]);
            acc[nt] = __builtin_amdgcn_mfma_f32_16x16x32_f16(af, bf, acc[nt], 0, 0, 0);
        }
    }

    float aS[4], aD[4];
#pragma unroll
    for (int nt = 0; nt < 4; ++nt) {
        aS[nt] = a_src[nt * 16 + m16];
        aD[nt] = a_dst[nt * 16 + m16];
    }
    int rowBaseW = blockIdx.x * 64 + wv * 16;
#pragma unroll
    for (int r = 0; r < 4; ++r) {
        int orow = rowBaseW + quad * 4 + r;
        bool ov = orow < nrows;
        if (ov) {
#pragma unroll
            for (int nt = 0; nt < 4; ++nt)
                outh[(size_t)orow * 64 + nt * 16 + m16] = __float2half(acc[nt][r]);
        }
        float ss = 0.f, dd = 0.f;
#pragma unroll
        for (int nt = 0; nt < 4; ++nt) {
            ss = fmaf(acc[nt][r], aS[nt], ss);
            dd = fmaf(acc[nt][r], aD[nt], dd);
        }
#pragma unroll
        for (int o = 1; o < 16; o <<= 1) {
            ss += __shfl_xor(ss, o, 64);
            dd += __shfl_xor(dd, o, 64);
        }
        if (ov && m16 == 0) {
            as_out[orow] = ss;
            ad_out[orow] = dd;
        }
    }
}

// ---------------- aggregation ----------------

// layer 1 (R12): XCD channel-sliced. Grid = nodeGroups x 8 slices; slice =
// blockIdx.x % 8 -> pinned to one XCD (round-robin dispatch), so each XCD's
// L2 only holds a 16-channel slice of h1h (50000 x 32B = 1.6MB, L2-resident)
// + asrc (800KB). One wave per (node, slice): lane = {eslot(4b), sub(2b)} —
// 16 edges in flight, each edge's 16 channels = 4 lanes x f16x4. col[] read
// directly (no shfl). 32-edge batches (2 groups issued before consumption).
__global__ __launch_bounds__(256) void agg1_kernel(const __half* __restrict__ h1h,
                                                   const float* __restrict__ asrc,
                                                   const float* __restrict__ adst,
                                                   const int* __restrict__ row_ptr,
                                                   const unsigned short* __restrict__ col,
                                                   const float* __restrict__ b1,
                                                   __half* __restrict__ out, int n) {
    unsigned bid = blockIdx.x;
    int slice = (int)(bid & 7u);      // 16-channel slice, XCD-pinned
    int ng = (int)(bid >> 3);
    int wave = threadIdx.x >> 6;
    int lane = threadIdx.x & 63;
    int node = ng * 4 + wave;
    if (node >= n) return;
    int eslot = lane >> 2;            // 16 edge slots
    int sub = lane & 3;               // 4 x f16x4 chunks = 16 channels
    int head = slice >> 1;
    const char* __restrict__ h1c = (const char*)h1h;
    const char* __restrict__ asc = (const char*)asrc;
    unsigned coff = ((unsigned)slice << 5) | ((unsigned)sub << 3);  // <256
    unsigned aoff = (unsigned)head << 2;
    float ad = adst[node * 4 + head];
    int start = row_ptr[node], end = row_ptr[node + 1];
    float a0 = 0.f, a1 = 0.f, a2 = 0.f, a3 = 0.f, s = 0.f;
    for (int base = start; base < end; base += 32) {
        // issue phase: 2 edge-groups (col -> row gather + asrc gather)
        int iA = base + eslot;
        int iB = iA + 16;
        int sA = (int)col[min(iA, end - 1)];
        int sB = (int)col[min(iB, end - 1)];
        f16x4 vA = *(const f16x4*)(h1c + ((((unsigned)sA) << 8) | coff));
        f16x4 vB = *(const f16x4*)(h1c + ((((unsigned)sB) << 8) | coff));
        float eA = *(const float*)(asc + ((((unsigned)sA) << 4) | aoff)) + ad;
        float eB = *(const float*)(asc + ((((unsigned)sB) << 4) | aoff)) + ad;
        // consume phase
        eA = fmaxf(eA, LRELU_SLOPE * eA);
        eB = fmaxf(eB, LRELU_SLOPE * eB);
        float pA = (iA < end) ? __expf(eA) : 0.f;
        float pB = (iB < end) ? __expf(eB) : 0.f;
        a0 = fmaf(pA, (float)vA[0], a0);
        a1 = fmaf(pA, (float)vA[1], a1);
        a2 = fmaf(pA, (float)vA[2], a2);
        a3 = fmaf(pA, (float)vA[3], a3);
        a0 = fmaf(pB, (float)vB[0], a0);
        a1 = fmaf(pB, (float)vB[1], a1);
        a2 = fmaf(pB, (float)vB[2], a2);
        a3 = fmaf(pB, (float)vB[3], a3);
        s += pA + pB;
    }
    // reduce across the 16 edge slots (strides 4..32); sub axis untouched
#pragma unroll
    for (int o = 4; o < 64; o <<= 1) {
        a0 += __shfl_xor(a0, o, 64);
        a1 += __shfl_xor(a1, o, 64);
        a2 += __shfl_xor(a2, o, 64);
        a3 += __shfl_xor(a3, o, 64);
        s  += __shfl_xor(s, o, 64);
    }
    if (lane < 4) {  // eslot == 0 lanes hold the 4 chunks of this slice
        float inv = 1.f / (s + 1e-16f);
        float4 bb = ((const float4*)b1)[slice * 4 + sub];
        f16x4 o;
        o[0] = (_Float16)fmaxf(fmaf(a0, inv, bb.x), 0.f);  // relu between layers
        o[1] = (_Float16)fmaxf(fmaf(a1, inv, bb.y), 0.f);
        o[2] = (_Float16)fmaxf(fmaf(a2, inv, bb.z), 0.f);
        o[3] = (_Float16)fmaxf(fmaf(a3, inv, bb.w), 0.f);
        ((f16x4*)out)[node * 32 + slice * 4 + sub] = o;
    }
}

// layer 2: one wave per dst node. Quarter-wave per edge row: lane = {q(2),m(4)},
// lane m covers channels [4m,4m+4) of 64. R11: 12-edge batches (3 per quarter),
// 3 row + 3 asrc gathers in flight per lane.
__global__ __launch_bounds__(256) void agg2_kernel(const __half* __restrict__ h2bh,
                                                   const float* __restrict__ asrc,
                                                   const float* __restrict__ adst,
                                                   const int* __restrict__ row_ptr,
                                                   const unsigned short* __restrict__ col,
                                                   const float* __restrict__ b2,
                                                   float* __restrict__ out, int n) {
    int wave = threadIdx.x >> 6;
    int lane = threadIdx.x & 63;
    int node = blockIdx.x * 4 + wave;
    if (node >= n) return;
    int q = lane >> 4;
    int m = lane & 15;             // f16x4 chunk index within 64-ch row
    const char* __restrict__ h2c = (const char*)h2bh;
    const char* __restrict__ asc = (const char*)asrc;
    unsigned moff = (unsigned)m << 3;   // byte offset of lane's 8B chunk (<128)
    float ad = adst[node];
    int start = row_ptr[node], end = row_ptr[node + 1];
    float a0c = 0.f, a1c = 0.f, a2c = 0.f, a3c = 0.f, s = 0.f;
    for (int base = start; base < end; base += 64) {
        int cnt = min(64, end - base);
        int idx = base + lane;
        int myS = (idx < end) ? (int)col[idx] : 0;
        for (int j = 0; j < cnt; j += 12) {
            int jj[3];
            int sv[3];
#pragma unroll
            for (int k = 0; k < 3; ++k) {
                jj[k] = j + 4 * k + q;
                sv[k] = __shfl(myS, jj[k], 64);
            }
            f16x4 v[3];
            float as[3];
#pragma unroll
            for (int k = 0; k < 3; ++k) {
                v[k]  = *(const f16x4*)(h2c + ((((unsigned)sv[k]) << 7) | moff));
                as[k] = *(const float*)(asc + (((unsigned)sv[k]) << 2));
            }
#pragma unroll
            for (int k = 0; k < 3; ++k) {
                float e = as[k] + ad;
                e = fmaxf(e, LRELU_SLOPE * e);
                float p = (jj[k] < cnt) ? __expf(e) : 0.f;
                a0c = fmaf(p, (float)v[k][0], a0c);
                a1c = fmaf(p, (float)v[k][1], a1c);
                a2c = fmaf(p, (float)v[k][2], a2c);
                a3c = fmaf(p, (float)v[k][3], a3c);
                s += p;
            }
        }
    }
#pragma unroll
    for (int o = 16; o <= 32; o <<= 1) {
        a0c += __shfl_xor(a0c, o, 64);
        a1c += __shfl_xor(a1c, o, 64);
        a2c += __shfl_xor(a2c, o, 64);
        a3c += __shfl_xor(a3c, o, 64);
        s   += __shfl_xor(s, o, 64);
    }
    if (lane < 16) {
        float inv = 1.f / (s + 1e-16f);
        float4 bb = ((const float4*)b2)[m];
        float4 o;
        o.x = fmaf(a0c, inv, bb.x);
        o.y = fmaf(a1c, inv, bb.y);
        o.z = fmaf(a2c, inv, bb.z);
        o.w = fmaf(a3c, inv, bb.w);
        ((float4*)(out + (size_t)node * 64))[m] = o;
    }
}

// ---------------- launch ----------------

extern "C" void kernel_launch(void* const* d_in, const int* in_sizes, int n_in,
                              void* d_out, int out_size, void* d_ws, size_t ws_size,
                              hipStream_t stream) {
    const float* x      = (const float*)d_in[0];
    const int*   ei     = (const int*)d_in[1];
    const float* W1     = (const float*)d_in[2];
    const float* a_src1 = (const float*)d_in[3];
    const float* a_dst1 = (const float*)d_in[4];
    const float* b1     = (const float*)d_in[5];
    const float* W2     = (const float*)d_in[6];
    const float* a_src2 = (const float*)d_in[7];
    const float* a_dst2 = (const float*)d_in[8];
    const float* b2     = (const float*)d_in[9];
    float* out = (float*)d_out;

    const int N = in_sizes[0] / 128;
    const int E = in_sizes[1] / 2;
    const int total = E + N;
    const int nBuckets = (N + 255) >> 8;   // 196

    char* ws = (char*)d_ws;
    size_t off = 0;
    auto alloc = [&](size_t bytes) {
        void* p = ws + off;
        off += (bytes + 255) & ~(size_t)255;
        return p;
    };
    // Region A: records+hist (CSR build), then h2in fp16 (agg1->gemm2).
    float* regionA = (float*)alloc((size_t)N * 128 * 4);
    __half* h1h   = (__half*)alloc((size_t)N * 128 * 2);
    __half* h2bh  = (__half*)alloc((size_t)N * 64 * 2);
    float* asrc1  = (float*)alloc((size_t)N * 4 * 4);
    float* adst1  = (float*)alloc((size_t)N * 4 * 4);
    float* asrc2  = (float*)alloc((size_t)N * 4);
    float* adst2  = (float*)alloc((size_t)N * 4);
    int*   deg    = (int*)alloc((size_t)N * 4);
    int*   row_ptr= (int*)alloc((size_t)(N + 1) * 4);
    int*   gfill  = (int*)alloc((size_t)nBuckets * 4);
    int*   bsums  = (int*)alloc((size_t)nBuckets * 4);
    unsigned short* col = (unsigned short*)alloc((size_t)total * 2);

    unsigned int* records = (unsigned int*)regionA;          // 12.8MB
    int* hist = (int*)(regionA + (size_t)NBMAX * BCAP);      // +400KB
    __half* h2in = (__half*)regionA;                         // after CSR build done
    (void)ws_size; (void)n_in; (void)out_size;

    const int* ei_src = ei;
    const int* ei_dst = ei + E;

    // CSR build (counting sort by dst bucket)
    const int chunk = (E + NBLK - 1) / NBLK;
    hist_kernel<<<NBLK, 256, 0, stream>>>(ei_dst, hist, E, chunk);
    bucket_scan_kernel<<<nBuckets, NBLK, 0, stream>>>(hist, gfill);
    scatter2_kernel<<<NBLK, 256, 0, stream>>>(ei_src, ei_dst, hist, records, E, chunk);
    deg_kernel<<<nBuckets, 256, 0, stream>>>(records, gfill, deg, N);
    scan_blocksums_kernel<<<1, 256, 0, stream>>>(gfill, bsums, row_ptr, nBuckets, N, total);
    scan_down_kernel<<<nBuckets, 256, 0, stream>>>(deg, bsums, row_ptr, N);
    csr_scatter_kernel<<<nBuckets, 256, 0, stream>>>(records, gfill, row_ptr, col, N);

    // layer 1
    gemm1_mfma_kernel<<<(N + 63) / 64, 256, 0, stream>>>(x, W1, h1h, a_src1, a_dst1,
                                                         asrc1, adst1, N);
    agg1_kernel<<<((N + 3) / 4) * 8, 256, 0, stream>>>(h1h, asrc1, adst1,
                                                       row_ptr, col, b1, h2in, N);

    // layer 2
    gemm2_mfma_kernel<<<(N + 63) / 64, 256, 0, stream>>>(h2in, W2, h2bh, a_src2, a_dst2,
                                                         asrc2, adst2, N);
    agg2_kernel<<<(N + 3) / 4, 256, 0, stream>>>(h2bh, asrc2, adst2,
                                                 row_ptr, col, b2, out, N);
}

// Round 4
// 244.660 us; speedup vs baseline: 1.5960x; 1.5960x over previous
//
#include <hip/hip_runtime.h>
#include <hip/hip_bf16.h>
#include <hip/hip_fp16.h>

// ---------------------------------------------------------------------------
// 2-layer GAT, N=50000, E=1.6M (+N self loops).
// CSR build (counting sort) -> GEMM1 [fp16 MFMA, fused alpha] -> agg1(fp16 out)
//  -> GEMM2 [fp16 MFMA, fused alpha] -> agg2 -> d_out.
// Softmax computed without max-shift (shift-invariant; |e| ~ 1.5).
// R2: hierarchical scan. R3: col[] uint16. R4: fp16 gather payload.
// R6: counting-sort CSR build. R9: MFMA GEMMs (v_mfma_f32_16x16x32_f16).
// R10/R11: wide-lane gather layouts + 12-edge SW pipeline.
// R12 (reverted): XCD channel-slicing failed — 64B-line splitting + L2 thrash
//      (FETCH 171->448MB). Lesson: agg1@54us IS the random-line ceiling
//      (~171MB @ ~3.4TB/s L2-miss path); only traffic cuts can beat it.
// R13: agg1 back to R11. agg2 -> direct-col layout (8 lanes/edge, f16x8 16B
//      gathers, no shfl). CSR: deg+scan_down fused into csr_scatter (-2
//      dispatches, -deg round trip).
// ---------------------------------------------------------------------------

#define LRELU_SLOPE 0.2f
#define NBMAX 200        // max dst buckets (N <= 51200)
#define NBLK  512        // blocks in hist/scatter passes
#define BCAP  16384      // per-bucket record capacity (mean ~8163)
#define CAPIMG 16384     // csr_scatter LDS image entries

typedef _Float16 f16x8 __attribute__((ext_vector_type(8)));
typedef _Float16 f16x4 __attribute__((ext_vector_type(4)));
typedef float f32x4 __attribute__((ext_vector_type(4)));

// ---------------- CSR build ----------------

__global__ __launch_bounds__(256) void hist_kernel(const int* __restrict__ ei_dst,
                                                   int* __restrict__ hist, int E, int chunk) {
    __shared__ int h[NBMAX];
    int t = threadIdx.x;
    for (int i = t; i < NBMAX; i += 256) h[i] = 0;
    __syncthreads();
    int begin = blockIdx.x * chunk;
    int endE = min(E, begin + chunk);
    for (int e = begin + t; e < endE; e += 256) atomicAdd(&h[ei_dst[e] >> 8], 1);
    __syncthreads();
    for (int i = t; i < NBMAX; i += 256) hist[i * NBLK + blockIdx.x] = h[i];
}

__global__ __launch_bounds__(512) void bucket_scan_kernel(int* __restrict__ hist,
                                                          int* __restrict__ gfill) {
    __shared__ int buf[2][NBLK];
    int b = blockIdx.x, t = threadIdx.x;
    buf[0][t] = hist[b * NBLK + t];
    __syncthreads();
    int pi = 0;
#pragma unroll
    for (int off = 1; off < NBLK; off <<= 1) {
        int v = buf[pi][t];
        if (t >= off) v += buf[pi][t - off];
        buf[pi ^ 1][t] = v;
        __syncthreads();
        pi ^= 1;
    }
    hist[b * NBLK + t] = (t == 0) ? 0 : buf[pi][t - 1];
    if (t == 0) gfill[b] = buf[pi][NBLK - 1];
}

__global__ __launch_bounds__(256) void scatter2_kernel(const int* __restrict__ ei_src,
                                                       const int* __restrict__ ei_dst,
                                                       const int* __restrict__ hist,
                                                       unsigned int* __restrict__ records,
                                                       int E, int chunk) {
    __shared__ int base[NBMAX];
    __shared__ int lcnt[NBMAX];
    int t = threadIdx.x;
    for (int i = t; i < NBMAX; i += 256) {
        base[i] = hist[i * NBLK + blockIdx.x];
        lcnt[i] = 0;
    }
    __syncthreads();
    int begin = blockIdx.x * chunk;
    int endE = min(E, begin + chunk);
    for (int e = begin + t; e < endE; e += 256) {
        int s = ei_src[e], d = ei_dst[e];
        int bkt = d >> 8;
        unsigned int rec = (unsigned int)d | ((unsigned int)s << 16);
        int r = atomicAdd(&lcnt[bkt], 1);
        records[(size_t)bkt * BCAP + base[bkt] + r] = rec;
    }
}

__global__ __launch_bounds__(256) void scan_blocksums_kernel(const int* __restrict__ gfill,
                                                             int* __restrict__ bsums,
                                                             int* __restrict__ row_ptr,
                                                             int nblocks, int n, int total) {
    __shared__ int buf[2][256];
    int t = threadIdx.x;
    int v0 = 0;
    if (t < nblocks) v0 = gfill[t] + min(256, n - (t << 8));
    buf[0][t] = v0;
    __syncthreads();
    int pi = 0;
#pragma unroll
    for (int off = 1; off < 256; off <<= 1) {
        int v = buf[pi][t];
        if (t >= off) v += buf[pi][t - off];
        buf[pi ^ 1][t] = v;
        __syncthreads();
        pi ^= 1;
    }
    if (t < nblocks) bsums[t] = (t == 0) ? 0 : buf[pi][t - 1];
    if (t == 0) row_ptr[n] = total;
}

// R13: fused degree-count + block scan + row_ptr write + scatter (replaces
// deg_kernel, scan_down_kernel, csr_scatter_kernel).
__global__ __launch_bounds__(256) void csr_fused_kernel(const unsigned int* __restrict__ records,
                                                        const int* __restrict__ gfill,
                                                        const int* __restrict__ bsums,
                                                        int* __restrict__ row_ptr,
                                                        unsigned short* __restrict__ col,
                                                        int N) {
    __shared__ unsigned short img[CAPIMG];
    __shared__ int cnt[2][256];
    __shared__ int lfill[256];
    int t = threadIdx.x, b = blockIdx.x;
    int bBase = b << 8;
    int bEnd = min(bBase + 256, N);
    int rbase = bsums[b];
    int c = gfill[b];
    int size = c + (bEnd - bBase);
    bool lds = (size <= CAPIMG);
    const unsigned int* r = records + (size_t)b * BCAP;
    int gi = bBase + t;
    cnt[0][t] = (gi < bEnd) ? 1 : 0;   // self loop counts
    __syncthreads();
    for (int i = t; i < c; i += 256) atomicAdd(&cnt[0][r[i] & 255], 1);
    __syncthreads();
    int d = cnt[0][t];                 // this node's degree (incl self)
    int pi = 0;
#pragma unroll
    for (int off = 1; off < 256; off <<= 1) {
        int v = cnt[pi][t];
        if (t >= off) v += cnt[pi][t - off];
        cnt[pi ^ 1][t] = v;
        __syncthreads();
        pi ^= 1;
    }
    int local = cnt[pi][t] - d;        // exclusive prefix within bucket
    if (gi < bEnd) {
        row_ptr[gi] = rbase + local;
        lfill[t] = local + 1;          // slot 0 = self loop
        if (lds) img[local] = (unsigned short)gi;
        else col[rbase + local] = (unsigned short)gi;
    }
    __syncthreads();
    for (int i = t; i < c; i += 256) {
        unsigned int rec = r[i];
        int d8 = rec & 255;
        unsigned short s = (unsigned short)(rec >> 16);
        int p = atomicAdd(&lfill[d8], 1);
        if (lds) img[p] = s;
        else col[rbase + p] = s;
    }
    __syncthreads();
    if (lds) {
        for (int i = t; i < size; i += 256) col[rbase + i] = img[i];
    }
}

// ---------------- GEMM1: X fp32 [n,128] @ W1 [128,128] -> h1h fp16 + alphas ----
// Per block: 64 rows (4 waves x 16). MFMA 16x16x32 f16; W^T staged fp16 LDS.

__global__ __launch_bounds__(256) void gemm1_mfma_kernel(const float* __restrict__ X,
                                                         const float* __restrict__ W,
                                                         __half* __restrict__ outh,
                                                         const float* __restrict__ a_src,
                                                         const float* __restrict__ a_dst,
                                                         float* __restrict__ as_out,
                                                         float* __restrict__ ad_out, int nrows) {
    constexpr int KP = 136;  // padded k-stride in halves
    __shared__ _Float16 wlds[128 * KP];  // wlds[n][k] = W[k][n]
    int t = threadIdx.x;
    int wv = t >> 6, lane = t & 63;
    int quad = lane >> 4, m16 = lane & 15;
    // stage W^T as fp16
    for (int i = t; i < 4096; i += 256) {  // 128*128/4
        int k = i >> 5;
        int n0 = (i & 31) << 2;
        float4 v = *(const float4*)(W + k * 128 + n0);
        wlds[(n0 + 0) * KP + k] = (_Float16)v.x;
        wlds[(n0 + 1) * KP + k] = (_Float16)v.y;
        wlds[(n0 + 2) * KP + k] = (_Float16)v.z;
        wlds[(n0 + 3) * KP + k] = (_Float16)v.w;
    }
    __syncthreads();

    int row = blockIdx.x * 64 + wv * 16 + m16;
    int rowC = min(row, nrows - 1);
    const float* xp = X + (size_t)rowC * 128;

    f32x4 acc[8];
#pragma unroll
    for (int nt = 0; nt < 8; ++nt) acc[nt] = (f32x4)0.f;

    for (int kt = 0; kt < 128; kt += 32) {
        float4 v0 = *(const float4*)(xp + kt + quad * 8);
        float4 v1 = *(const float4*)(xp + kt + quad * 8 + 4);
        f16x8 af;
        af[0] = (_Float16)v0.x; af[1] = (_Float16)v0.y;
        af[2] = (_Float16)v0.z; af[3] = (_Float16)v0.w;
        af[4] = (_Float16)v1.x; af[5] = (_Float16)v1.y;
        af[6] = (_Float16)v1.z; af[7] = (_Float16)v1.w;
#pragma unroll
        for (int nt = 0; nt < 8; ++nt) {
            f16x8 bf = *(const f16x8*)(&wlds[(nt * 16 + m16) * KP + kt + quad * 8]);
            acc[nt] = __builtin_amdgcn_mfma_f32_16x16x32_f16(af, bf, acc[nt], 0, 0, 0);
        }
    }

    // per-lane alpha coefficients for its column in each tile
    float aS[8], aD[8];
#pragma unroll
    for (int nt = 0; nt < 8; ++nt) {
        aS[nt] = a_src[nt * 16 + m16];
        aD[nt] = a_dst[nt * 16 + m16];
    }
    int rowBaseW = blockIdx.x * 64 + wv * 16;
#pragma unroll
    for (int r = 0; r < 4; ++r) {
        int orow = rowBaseW + quad * 4 + r;
        bool ov = orow < nrows;
        // fp16 store of C row segment
        if (ov) {
#pragma unroll
            for (int nt = 0; nt < 8; ++nt)
                outh[(size_t)orow * 128 + nt * 16 + m16] = __float2half(acc[nt][r]);
        }
        // alpha: per head h, reduce cols (2 tiles x 16 lanes)
#pragma unroll
        for (int h = 0; h < 4; ++h) {
            float ss = acc[2 * h][r] * aS[2 * h] + acc[2 * h + 1][r] * aS[2 * h + 1];
            float dd = acc[2 * h][r] * aD[2 * h] + acc[2 * h + 1][r] * aD[2 * h + 1];
#pragma unroll
            for (int o = 1; o < 16; o <<= 1) {
                ss += __shfl_xor(ss, o, 64);
                dd += __shfl_xor(dd, o, 64);
            }
            if (ov && m16 == h) {
                as_out[orow * 4 + h] = ss;
                ad_out[orow * 4 + h] = dd;
            }
        }
    }
}

// ---------------- GEMM2: h2in fp16 [n,128] @ W2 [128,64] -> h2bh fp16 + alphas --

__global__ __launch_bounds__(256) void gemm2_mfma_kernel(const __half* __restrict__ Xh,
                                                         const float* __restrict__ W,
                                                         __half* __restrict__ outh,
                                                         const float* __restrict__ a_src,
                                                         const float* __restrict__ a_dst,
                                                         float* __restrict__ as_out,
                                                         float* __restrict__ ad_out, int nrows) {
    constexpr int KP = 136;
    __shared__ _Float16 wlds[64 * KP];  // wlds[n][k] = W[k][n]
    int t = threadIdx.x;
    int wv = t >> 6, lane = t & 63;
    int quad = lane >> 4, m16 = lane & 15;
    for (int i = t; i < 2048; i += 256) {  // 128*64/4
        int k = i >> 4;
        int n0 = (i & 15) << 2;
        float4 v = *(const float4*)(W + k * 64 + n0);
        wlds[(n0 + 0) * KP + k] = (_Float16)v.x;
        wlds[(n0 + 1) * KP + k] = (_Float16)v.y;
        wlds[(n0 + 2) * KP + k] = (_Float16)v.z;
        wlds[(n0 + 3) * KP + k] = (_Float16)v.w;
    }
    __syncthreads();

    int row = blockIdx.x * 64 + wv * 16 + m16;
    int rowC = min(row, nrows - 1);
    const _Float16* xp = (const _Float16*)Xh + (size_t)rowC * 128;

    f32x4 acc[4];
#pragma unroll
    for (int nt = 0; nt < 4; ++nt) acc[nt] = (f32x4)0.f;

    for (int kt = 0; kt < 128; kt += 32) {
        f16x8 af = *(const f16x8*)(xp + kt + quad * 8);
#pragma unroll
        for (int nt = 0; nt < 4; ++nt) {
            f16x8 bf = *(const f16x8*)(&wlds[(nt * 16 + m16) * KP + kt + quad * 8]);
            acc[nt] = __builtin_amdgcn_mfma_f32_16x16x32_f16(af, bf, acc[nt], 0, 0, 0);
        }
    }

    float aS[4], aD[4];
#pragma unroll
    for (int nt = 0; nt < 4; ++nt) {
        aS[nt] = a_src[nt * 16 + m16];
        aD[nt] = a_dst[nt * 16 + m16];
    }
    int rowBaseW = blockIdx.x * 64 + wv * 16;
#pragma unroll
    for (int r = 0; r < 4; ++r) {
        int orow = rowBaseW + quad * 4 + r;
        bool ov = orow < nrows;
        if (ov) {
#pragma unroll
            for (int nt = 0; nt < 4; ++nt)
                outh[(size_t)orow * 64 + nt * 16 + m16] = __float2half(acc[nt][r]);
        }
        float ss = 0.f, dd = 0.f;
#pragma unroll
        for (int nt = 0; nt < 4; ++nt) {
            ss = fmaf(acc[nt][r], aS[nt], ss);
            dd = fmaf(acc[nt][r], aD[nt], dd);
        }
#pragma unroll
        for (int o = 1; o < 16; o <<= 1) {
            ss += __shfl_xor(ss, o, 64);
            dd += __shfl_xor(dd, o, 64);
        }
        if (ov && m16 == 0) {
            as_out[orow] = ss;
            ad_out[orow] = dd;
        }
    }
}

// ---------------- aggregation ----------------

// layer 1 (R11 form — at the random-line traffic ceiling): one wave per dst
// node. Half-wave per edge row: lane = {half(1),m(5)}, lane m covers channels
// [4m,4m+4) via one 8B f16x4 gather. 12-edge batches, 6 row + 6 asrc gathers
// in flight per lane. Guarded slots gather row 0 (L1-hot).
__global__ __launch_bounds__(256) void agg1_kernel(const __half* __restrict__ h1h,
                                                   const float* __restrict__ asrc,
                                                   const float* __restrict__ adst,
                                                   const int* __restrict__ row_ptr,
                                                   const unsigned short* __restrict__ col,
                                                   const float* __restrict__ b1,
                                                   __half* __restrict__ out, int n) {
    int wave = threadIdx.x >> 6;
    int lane = threadIdx.x & 63;
    int node = blockIdx.x * 4 + wave;
    if (node >= n) return;
    int half = lane >> 5;
    int m = lane & 31;             // f16x4 chunk index within 128-ch row
    int head = m >> 3;             // 4 heads x 8 chunks
    const char* __restrict__ h1c = (const char*)h1h;
    const char* __restrict__ asc = (const char*)asrc;
    unsigned moff = (unsigned)m << 3;    // byte offset of lane's 8B chunk (<256)
    unsigned aoff = (unsigned)head << 2; // byte offset into 16B asrc row
    float ad = adst[node * 4 + head];
    int start = row_ptr[node], end = row_ptr[node + 1];
    float a0c = 0.f, a1c = 0.f, a2c = 0.f, a3c = 0.f, s = 0.f;
    for (int base = start; base < end; base += 64) {
        int cnt = min(64, end - base);
        int idx = base + lane;
        int myS = (idx < end) ? (int)col[idx] : 0;
        for (int j = 0; j < cnt; j += 12) {
            // ---- issue phase: 6 row-gathers + 6 asrc gathers per lane ----
            int jj[6];
            int sv[6];
#pragma unroll
            for (int k = 0; k < 6; ++k) {
                jj[k] = j + 2 * k + half;          // >=64 wraps in shfl; guarded below
                sv[k] = __shfl(myS, jj[k], 64);
            }
            f16x4 v[6];
            float as[6];
#pragma unroll
            for (int k = 0; k < 6; ++k) {
                v[k]  = *(const f16x4*)(h1c + ((((unsigned)sv[k]) << 8) | moff));
                as[k] = *(const float*)(asc + ((((unsigned)sv[k]) << 4) | aoff));
            }
            // ---- consume phase ----
#pragma unroll
            for (int k = 0; k < 6; ++k) {
                float e = as[k] + ad;
                e = fmaxf(e, LRELU_SLOPE * e);
                float p = (jj[k] < cnt) ? __expf(e) : 0.f;
                a0c = fmaf(p, (float)v[k][0], a0c);
                a1c = fmaf(p, (float)v[k][1], a1c);
                a2c = fmaf(p, (float)v[k][2], a2c);
                a3c = fmaf(p, (float)v[k][3], a3c);
                s += p;
            }
        }
    }
    a0c += __shfl_xor(a0c, 32, 64);
    a1c += __shfl_xor(a1c, 32, 64);
    a2c += __shfl_xor(a2c, 32, 64);
    a3c += __shfl_xor(a3c, 32, 64);
    s   += __shfl_xor(s, 32, 64);
    if (half == 0) {
        float inv = 1.f / (s + 1e-16f);
        float4 bb = ((const float4*)b1)[m];
        f16x4 o;
        o[0] = (_Float16)fmaxf(fmaf(a0c, inv, bb.x), 0.f);  // relu between layers
        o[1] = (_Float16)fmaxf(fmaf(a1c, inv, bb.y), 0.f);
        o[2] = (_Float16)fmaxf(fmaf(a2c, inv, bb.z), 0.f);
        o[3] = (_Float16)fmaxf(fmaf(a3c, inv, bb.w), 0.f);
        ((f16x4*)out)[node * 32 + m] = o;
    }
}

// layer 2 (R13): one wave per dst node, direct-col layout. lane =
// {eslot(3b), sub(3b)}: 8 edge slots x 8 lanes; lane sub covers channels
// [8*sub, 8*sub+8) via one 16B f16x8 gather. col[] read directly per eslot
// (broadcast-coalesced), no shfl for indices. 2 groups (16 edges) in flight.
__global__ __launch_bounds__(256) void agg2_kernel(const __half* __restrict__ h2bh,
                                                   const float* __restrict__ asrc,
                                                   const float* __restrict__ adst,
                                                   const int* __restrict__ row_ptr,
                                                   const unsigned short* __restrict__ col,
                                                   const float* __restrict__ b2,
                                                   float* __restrict__ out, int n) {
    int wave = threadIdx.x >> 6;
    int lane = threadIdx.x & 63;
    int node = blockIdx.x * 4 + wave;
    if (node >= n) return;
    int eslot = lane >> 3;         // 8 edge slots
    int sub = lane & 7;            // 8 x f16x8 chunks = 64 ch
    const char* __restrict__ h2c = (const char*)h2bh;
    unsigned coff = (unsigned)sub << 4;   // byte offset of lane's 16B chunk (<128)
    float ad = adst[node];
    int start = row_ptr[node], end = row_ptr[node + 1];
    float acc[8];
#pragma unroll
    for (int c = 0; c < 8; ++c) acc[c] = 0.f;
    float s = 0.f;
    for (int base = start; base < end; base += 16) {
        // issue phase: 2 edge-groups
        int iA = base + eslot;
        int iB = iA + 8;
        int sA = (int)col[min(iA, end - 1)];
        int sB = (int)col[min(iB, end - 1)];
        f16x8 vA = *(const f16x8*)(h2c + ((((unsigned)sA) << 7) | coff));
        f16x8 vB = *(const f16x8*)(h2c + ((((unsigned)sB) << 7) | coff));
        float eA = asrc[sA] + ad;
        float eB = asrc[sB] + ad;
        // consume phase
        eA = fmaxf(eA, LRELU_SLOPE * eA);
        eB = fmaxf(eB, LRELU_SLOPE * eB);
        float pA = (iA < end) ? __expf(eA) : 0.f;
        float pB = (iB < end) ? __expf(eB) : 0.f;
#pragma unroll
        for (int c = 0; c < 8; ++c) acc[c] = fmaf(pA, (float)vA[c], acc[c]);
#pragma unroll
        for (int c = 0; c < 8; ++c) acc[c] = fmaf(pB, (float)vB[c], acc[c]);
        s += pA + pB;
    }
    // reduce across the 8 edge slots (strides 8..32); sub axis untouched
#pragma unroll
    for (int o = 8; o < 64; o <<= 1) {
#pragma unroll
        for (int c = 0; c < 8; ++c) acc[c] += __shfl_xor(acc[c], o, 64);
        s += __shfl_xor(s, o, 64);
    }
    if (lane < 8) {  // eslot == 0 lanes hold the 8 chunks
        float inv = 1.f / (s + 1e-16f);
        float4 bb0 = ((const float4*)b2)[sub * 2];
        float4 bb1 = ((const float4*)b2)[sub * 2 + 1];
        float4 o0, o1;
        o0.x = fmaf(acc[0], inv, bb0.x);
        o0.y = fmaf(acc[1], inv, bb0.y);
        o0.z = fmaf(acc[2], inv, bb0.z);
        o0.w = fmaf(acc[3], inv, bb0.w);
        o1.x = fmaf(acc[4], inv, bb1.x);
        o1.y = fmaf(acc[5], inv, bb1.y);
        o1.z = fmaf(acc[6], inv, bb1.z);
        o1.w = fmaf(acc[7], inv, bb1.w);
        ((float4*)(out + (size_t)node * 64))[sub * 2] = o0;
        ((float4*)(out + (size_t)node * 64))[sub * 2 + 1] = o1;
    }
}

// ---------------- launch ----------------

extern "C" void kernel_launch(void* const* d_in, const int* in_sizes, int n_in,
                              void* d_out, int out_size, void* d_ws, size_t ws_size,
                              hipStream_t stream) {
    const float* x      = (const float*)d_in[0];
    const int*   ei     = (const int*)d_in[1];
    const float* W1     = (const float*)d_in[2];
    const float* a_src1 = (const float*)d_in[3];
    const float* a_dst1 = (const float*)d_in[4];
    const float* b1     = (const float*)d_in[5];
    const float* W2     = (const float*)d_in[6];
    const float* a_src2 = (const float*)d_in[7];
    const float* a_dst2 = (const float*)d_in[8];
    const float* b2     = (const float*)d_in[9];
    float* out = (float*)d_out;

    const int N = in_sizes[0] / 128;
    const int E = in_sizes[1] / 2;
    const int total = E + N;
    const int nBuckets = (N + 255) >> 8;   // 196

    char* ws = (char*)d_ws;
    size_t off = 0;
    auto alloc = [&](size_t bytes) {
        void* p = ws + off;
        off += (bytes + 255) & ~(size_t)255;
        return p;
    };
    // Region A: records+hist (CSR build), then h2in fp16 (agg1->gemm2).
    float* regionA = (float*)alloc((size_t)N * 128 * 4);
    __half* h1h   = (__half*)alloc((size_t)N * 128 * 2);
    __half* h2bh  = (__half*)alloc((size_t)N * 64 * 2);
    float* asrc1  = (float*)alloc((size_t)N * 4 * 4);
    float* adst1  = (float*)alloc((size_t)N * 4 * 4);
    float* asrc2  = (float*)alloc((size_t)N * 4);
    float* adst2  = (float*)alloc((size_t)N * 4);
    int*   row_ptr= (int*)alloc((size_t)(N + 1) * 4);
    int*   gfill  = (int*)alloc((size_t)nBuckets * 4);
    int*   bsums  = (int*)alloc((size_t)nBuckets * 4);
    unsigned short* col = (unsigned short*)alloc((size_t)total * 2);

    unsigned int* records = (unsigned int*)regionA;          // 12.8MB
    int* hist = (int*)(regionA + (size_t)NBMAX * BCAP);      // +400KB
    __half* h2in = (__half*)regionA;                         // after CSR build done
    (void)ws_size; (void)n_in; (void)out_size;

    const int* ei_src = ei;
    const int* ei_dst = ei + E;

    // CSR build (counting sort by dst bucket)
    const int chunk = (E + NBLK - 1) / NBLK;
    hist_kernel<<<NBLK, 256, 0, stream>>>(ei_dst, hist, E, chunk);
    bucket_scan_kernel<<<nBuckets, NBLK, 0, stream>>>(hist, gfill);
    scatter2_kernel<<<NBLK, 256, 0, stream>>>(ei_src, ei_dst, hist, records, E, chunk);
    scan_blocksums_kernel<<<1, 256, 0, stream>>>(gfill, bsums, row_ptr, nBuckets, N, total);
    csr_fused_kernel<<<nBuckets, 256, 0, stream>>>(records, gfill, bsums, row_ptr, col, N);

    // layer 1
    gemm1_mfma_kernel<<<(N + 63) / 64, 256, 0, stream>>>(x, W1, h1h, a_src1, a_dst1,
                                                         asrc1, adst1, N);
    agg1_kernel<<<(N + 3) / 4, 256, 0, stream>>>(h1h, asrc1, adst1,
                                                 row_ptr, col, b1, h2in, N);

    // layer 2
    gemm2_mfma_kernel<<<(N + 63) / 64, 256, 0, stream>>>(h2in, W2, h2bh, a_src2, a_dst2,
                                                         asrc2, adst2, N);
    agg2_kernel<<<(N + 3) / 4, 256, 0, stream>>>(h2bh, asrc2, adst2,
                                                 row_ptr, col, b2, out, N);
}

// Round 5
// 242.184 us; speedup vs baseline: 1.6123x; 1.0102x over previous
//
#include <hip/hip_runtime.h>
#include <hip/hip_bf16.h>
#include <hip/hip_fp16.h>

// ---------------------------------------------------------------------------
// 2-layer GAT, N=50000, E=1.6M (+N self loops).
// R14 pipeline (7 dispatches):
//   memset(gfill) -> K1 [scatter(ticket CSR) || gemm1-MFMA || alpha1 fp32 ||
//   wa2 build] -> scan_blocksums -> csr_fused -> agg1(+fused alpha2) ->
//   gemm2(pure) -> agg2.
// Key facts carried forward:
//  - agg1 @55us/171MB is the random-64B-line L2-miss ceiling (R11 MLP probe
//    +7%@3x in-flight; R12 XCD channel-slicing made it 3.8x WORSE). Leave it.
//  - alpha1 = X @ (W1 . a1) and alpha2 = h2in @ (W2 . a2): computing alphas
//    as fp32 mini-GEMMs removes the 128-shfl gemm1 epilogue and gemm2's
//    alpha epilogue entirely (reorder-only, more accurate than fp16 path).
//  - CSR: single-pass atomic-ticket scatter (order within bucket irrelevant;
//    csr_fused re-sorts per node) kills hist + bucket_scan.
// ---------------------------------------------------------------------------

#define LRELU_SLOPE 0.2f
#define NBMAX 200        // max dst buckets (N <= 51200)
#define NBLK  512        // blocks in scatter role
#define BCAP  16384      // per-bucket record capacity (mean ~8163)
#define CAPIMG 16384     // csr_fused LDS image entries

typedef _Float16 f16x8 __attribute__((ext_vector_type(8)));
typedef _Float16 f16x4 __attribute__((ext_vector_type(4)));
typedef float f32x4 __attribute__((ext_vector_type(4)));

// ---------------- K1: scatter || gemm1 || alpha1 || wa2 ----------------
// Roles by blockIdx.x:
//   [0, NBLK)                : counting+ticket scatter of edge records
//   [NBLK, NBLK+G1B)         : gemm1 MFMA (X fp32 [n,128] @ W1 -> h1h fp16)
//   [NBLK+G1B, NBLK+G1B+ALB) : alpha1 = X @ [W1.a_src1 | W1.a_dst1] (fp32)
//   [NBLK+G1B+ALB]           : wa2 = [W2.a_src2 | W2.a_dst2] (256 floats)

__global__ __launch_bounds__(256) void k1_kernel(
    const int* __restrict__ ei_src, const int* __restrict__ ei_dst,
    unsigned int* __restrict__ records, int* __restrict__ gfill,
    const float* __restrict__ X, const float* __restrict__ W1,
    __half* __restrict__ h1h,
    const float* __restrict__ a_src1, const float* __restrict__ a_dst1,
    float* __restrict__ asrc1, float* __restrict__ adst1,
    const float* __restrict__ W2,
    const float* __restrict__ a_src2, const float* __restrict__ a_dst2,
    float* __restrict__ wa2,
    int E, int chunk, int N, int G1B, int ALB) {
    __shared__ __align__(16) char smem[34816];
    int t = threadIdx.x;
    int bid = blockIdx.x;

    if (bid < NBLK) {
        // ---------------- scatter role ----------------
        int* cnt  = (int*)smem;           // NBMAX
        int* base = ((int*)smem) + NBMAX; // NBMAX
        for (int i = t; i < NBMAX; i += 256) cnt[i] = 0;
        __syncthreads();
        int begin = bid * chunk;
        int endE = min(E, begin + chunk);
        for (int e = begin + t; e < endE; e += 256) atomicAdd(&cnt[ei_dst[e] >> 8], 1);
        __syncthreads();
        for (int i = t; i < NBMAX; i += 256) {
            int c = cnt[i];
            base[i] = c ? atomicAdd(&gfill[i], c) : 0;
            cnt[i] = 0;
        }
        __syncthreads();
        for (int e = begin + t; e < endE; e += 256) {
            int s = ei_src[e], d = ei_dst[e];
            int bkt = d >> 8;
            unsigned int rec = (unsigned int)d | ((unsigned int)s << 16);
            int r = atomicAdd(&cnt[bkt], 1);
            records[(size_t)bkt * BCAP + base[bkt] + r] = rec;
        }
        return;
    }

    if (bid < NBLK + G1B) {
        // ---------------- gemm1 role (no alpha epilogue) ----------------
        constexpr int KP = 136;
        _Float16* wlds = (_Float16*)smem;  // wlds[n][k] = W1[k][n], 128xKP
        int gb = bid - NBLK;
        int wv = t >> 6, lane = t & 63;
        int quad = lane >> 4, m16 = lane & 15;
        for (int i = t; i < 4096; i += 256) {  // 128*128/4
            int k = i >> 5;
            int n0 = (i & 31) << 2;
            float4 v = *(const float4*)(W1 + k * 128 + n0);
            wlds[(n0 + 0) * KP + k] = (_Float16)v.x;
            wlds[(n0 + 1) * KP + k] = (_Float16)v.y;
            wlds[(n0 + 2) * KP + k] = (_Float16)v.z;
            wlds[(n0 + 3) * KP + k] = (_Float16)v.w;
        }
        __syncthreads();

        int row = gb * 64 + wv * 16 + m16;
        int rowC = min(row, N - 1);
        const float* xp = X + (size_t)rowC * 128;

        f32x4 acc[8];
#pragma unroll
        for (int nt = 0; nt < 8; ++nt) acc[nt] = (f32x4)0.f;

        for (int kt = 0; kt < 128; kt += 32) {
            float4 v0 = *(const float4*)(xp + kt + quad * 8);
            float4 v1 = *(const float4*)(xp + kt + quad * 8 + 4);
            f16x8 af;
            af[0] = (_Float16)v0.x; af[1] = (_Float16)v0.y;
            af[2] = (_Float16)v0.z; af[3] = (_Float16)v0.w;
            af[4] = (_Float16)v1.x; af[5] = (_Float16)v1.y;
            af[6] = (_Float16)v1.z; af[7] = (_Float16)v1.w;
#pragma unroll
            for (int nt = 0; nt < 8; ++nt) {
                f16x8 bf = *(const f16x8*)(&wlds[(nt * 16 + m16) * KP + kt + quad * 8]);
                acc[nt] = __builtin_amdgcn_mfma_f32_16x16x32_f16(af, bf, acc[nt], 0, 0, 0);
            }
        }

        int rowBaseW = gb * 64 + wv * 16;
#pragma unroll
        for (int r = 0; r < 4; ++r) {
            int orow = rowBaseW + quad * 4 + r;
            if (orow < N) {
#pragma unroll
                for (int nt = 0; nt < 8; ++nt)
                    h1h[(size_t)orow * 128 + nt * 16 + m16] = __float2half(acc[nt][r]);
            }
        }
        return;
    }

    int aid = bid - NBLK - G1B;
    if (aid < ALB) {
        // ---------------- alpha1 role: [N,128] @ [128,8] fp32 ----------------
        float* waL = (float*)smem;  // [8][128]
        {
            int k = t >> 1, grp = t & 1;
            const float* wrow = W1 + k * 128;
            const float* abase = grp ? a_dst1 : a_src1;
#pragma unroll
            for (int h = 0; h < 4; ++h) {
                const float* av = abase + h * 32;
                const float* wr = wrow + h * 32;
                float acc = 0.f;
                for (int c = 0; c < 32; ++c) acc += wr[c] * av[c];
                waL[(grp * 4 + h) * 128 + k] = acc;
            }
        }
        __syncthreads();
        int row = aid * 256 + t;
        if (row < N) {
            const float4* x4 = (const float4*)(X + (size_t)row * 128);
            float p[8];
#pragma unroll
            for (int o = 0; o < 8; ++o) p[o] = 0.f;
            for (int k4 = 0; k4 < 32; ++k4) {
                float4 xv = x4[k4];
#pragma unroll
                for (int o = 0; o < 8; ++o) {
                    float4 wv = ((const float4*)(waL + o * 128))[k4];
                    p[o] += xv.x * wv.x + xv.y * wv.y + xv.z * wv.z + xv.w * wv.w;
                }
            }
            float4 ps = {p[0], p[1], p[2], p[3]};
            float4 pd = {p[4], p[5], p[6], p[7]};
            ((float4*)asrc1)[row] = ps;
            ((float4*)adst1)[row] = pd;
        }
        return;
    }

    // ---------------- wa2 build block ----------------
    if (t < 128) {
        const float* wr = W2 + t * 64;
        float acc = 0.f;
        for (int c = 0; c < 64; ++c) acc += wr[c] * a_src2[c];
        wa2[t] = acc;
    } else {
        int k = t - 128;
        const float* wr = W2 + k * 64;
        float acc = 0.f;
        for (int c = 0; c < 64; ++c) acc += wr[c] * a_dst2[c];
        wa2[128 + k] = acc;
    }
}

// ---------------- CSR finalize ----------------

__global__ __launch_bounds__(256) void scan_blocksums_kernel(const int* __restrict__ gfill,
                                                             int* __restrict__ bsums,
                                                             int* __restrict__ row_ptr,
                                                             int nblocks, int n, int total) {
    __shared__ int buf[2][256];
    int t = threadIdx.x;
    int v0 = 0;
    if (t < nblocks) v0 = gfill[t] + min(256, n - (t << 8));
    buf[0][t] = v0;
    __syncthreads();
    int pi = 0;
#pragma unroll
    for (int off = 1; off < 256; off <<= 1) {
        int v = buf[pi][t];
        if (t >= off) v += buf[pi][t - off];
        buf[pi ^ 1][t] = v;
        __syncthreads();
        pi ^= 1;
    }
    if (t < nblocks) bsums[t] = (t == 0) ? 0 : buf[pi][t - 1];
    if (t == 0) row_ptr[n] = total;
}

// fused degree-count + block scan + row_ptr write + scatter
__global__ __launch_bounds__(256) void csr_fused_kernel(const unsigned int* __restrict__ records,
                                                        const int* __restrict__ gfill,
                                                        const int* __restrict__ bsums,
                                                        int* __restrict__ row_ptr,
                                                        unsigned short* __restrict__ col,
                                                        int N) {
    __shared__ unsigned short img[CAPIMG];
    __shared__ int cnt[2][256];
    __shared__ int lfill[256];
    int t = threadIdx.x, b = blockIdx.x;
    int bBase = b << 8;
    int bEnd = min(bBase + 256, N);
    int rbase = bsums[b];
    int c = gfill[b];
    int size = c + (bEnd - bBase);
    bool lds = (size <= CAPIMG);
    const unsigned int* r = records + (size_t)b * BCAP;
    int gi = bBase + t;
    cnt[0][t] = (gi < bEnd) ? 1 : 0;   // self loop counts
    __syncthreads();
    for (int i = t; i < c; i += 256) atomicAdd(&cnt[0][r[i] & 255], 1);
    __syncthreads();
    int d = cnt[0][t];                 // this node's degree (incl self)
    int pi = 0;
#pragma unroll
    for (int off = 1; off < 256; off <<= 1) {
        int v = cnt[pi][t];
        if (t >= off) v += cnt[pi][t - off];
        cnt[pi ^ 1][t] = v;
        __syncthreads();
        pi ^= 1;
    }
    int local = cnt[pi][t] - d;        // exclusive prefix within bucket
    if (gi < bEnd) {
        row_ptr[gi] = rbase + local;
        lfill[t] = local + 1;          // slot 0 = self loop
        if (lds) img[local] = (unsigned short)gi;
        else col[rbase + local] = (unsigned short)gi;
    }
    __syncthreads();
    for (int i = t; i < c; i += 256) {
        unsigned int rec = r[i];
        int d8 = rec & 255;
        unsigned short s = (unsigned short)(rec >> 16);
        int p = atomicAdd(&lfill[d8], 1);
        if (lds) img[p] = s;
        else col[rbase + p] = s;
    }
    __syncthreads();
    if (lds) {
        for (int i = t; i < size; i += 256) col[rbase + i] = img[i];
    }
}

// ---------------- GEMM2: h2in fp16 [n,128] @ W2 [128,64] -> h2bh fp16 ----

__global__ __launch_bounds__(256) void gemm2_mfma_kernel(const __half* __restrict__ Xh,
                                                         const float* __restrict__ W,
                                                         __half* __restrict__ outh, int nrows) {
    constexpr int KP = 136;
    __shared__ _Float16 wlds[64 * KP];  // wlds[n][k] = W[k][n]
    int t = threadIdx.x;
    int wv = t >> 6, lane = t & 63;
    int quad = lane >> 4, m16 = lane & 15;
    for (int i = t; i < 2048; i += 256) {  // 128*64/4
        int k = i >> 4;
        int n0 = (i & 15) << 2;
        float4 v = *(const float4*)(W + k * 64 + n0);
        wlds[(n0 + 0) * KP + k] = (_Float16)v.x;
        wlds[(n0 + 1) * KP + k] = (_Float16)v.y;
        wlds[(n0 + 2) * KP + k] = (_Float16)v.z;
        wlds[(n0 + 3) * KP + k] = (_Float16)v.w;
    }
    __syncthreads();

    int row = blockIdx.x * 64 + wv * 16 + m16;
    int rowC = min(row, nrows - 1);
    const _Float16* xp = (const _Float16*)Xh + (size_t)rowC * 128;

    f32x4 acc[4];
#pragma unroll
    for (int nt = 0; nt < 4; ++nt) acc[nt] = (f32x4)0.f;

    for (int kt = 0; kt < 128; kt += 32) {
        f16x8 af = *(const f16x8*)(xp + kt + quad * 8);
#pragma unroll
        for (int nt = 0; nt < 4; ++nt) {
            f16x8 bf = *(const f16x8*)(&wlds[(nt * 16 + m16) * KP + kt + quad * 8]);
            acc[nt] = __builtin_amdgcn_mfma_f32_16x16x32_f16(af, bf, acc[nt], 0, 0, 0);
        }
    }

    int rowBaseW = blockIdx.x * 64 + wv * 16;
#pragma unroll
    for (int r = 0; r < 4; ++r) {
        int orow = rowBaseW + quad * 4 + r;
        if (orow < nrows) {
#pragma unroll
            for (int nt = 0; nt < 4; ++nt)
                outh[(size_t)orow * 64 + nt * 16 + m16] = __float2half(acc[nt][r]);
        }
    }
}

// ---------------- aggregation ----------------

// layer 1 (R11 form, at the random-line ceiling) + fused alpha2 epilogue:
// asrc2/adst2[node] = h2in[node] . wa2{s,d} computed from the fp32 outputs.
__global__ __launch_bounds__(256) void agg1_kernel(const __half* __restrict__ h1h,
                                                   const float* __restrict__ asrc,
                                                   const float* __restrict__ adst,
                                                   const int* __restrict__ row_ptr,
                                                   const unsigned short* __restrict__ col,
                                                   const float* __restrict__ b1,
                                                   const float* __restrict__ wa2,
                                                   __half* __restrict__ out,
                                                   float* __restrict__ asrc2,
                                                   float* __restrict__ adst2, int n) {
    int wave = threadIdx.x >> 6;
    int lane = threadIdx.x & 63;
    int node = blockIdx.x * 4 + wave;
    if (node >= n) return;
    int half = lane >> 5;
    int m = lane & 31;             // f16x4 chunk index within 128-ch row
    int head = m >> 3;             // 4 heads x 8 chunks
    const char* __restrict__ h1c = (const char*)h1h;
    const char* __restrict__ asc = (const char*)asrc;
    unsigned moff = (unsigned)m << 3;    // byte offset of lane's 8B chunk (<256)
    unsigned aoff = (unsigned)head << 2; // byte offset into 16B asrc row
    float ad = adst[node * 4 + head];
    int start = row_ptr[node], end = row_ptr[node + 1];
    float a0c = 0.f, a1c = 0.f, a2c = 0.f, a3c = 0.f, s = 0.f;
    for (int base = start; base < end; base += 64) {
        int cnt = min(64, end - base);
        int idx = base + lane;
        int myS = (idx < end) ? (int)col[idx] : 0;
        for (int j = 0; j < cnt; j += 12) {
            // ---- issue phase: 6 row-gathers + 6 asrc gathers per lane ----
            int jj[6];
            int sv[6];
#pragma unroll
            for (int k = 0; k < 6; ++k) {
                jj[k] = j + 2 * k + half;          // >=64 wraps in shfl; guarded below
                sv[k] = __shfl(myS, jj[k], 64);
            }
            f16x4 v[6];
            float as[6];
#pragma unroll
            for (int k = 0; k < 6; ++k) {
                v[k]  = *(const f16x4*)(h1c + ((((unsigned)sv[k]) << 8) | moff));
                as[k] = *(const float*)(asc + ((((unsigned)sv[k]) << 4) | aoff));
            }
            // ---- consume phase ----
#pragma unroll
            for (int k = 0; k < 6; ++k) {
                float e = as[k] + ad;
                e = fmaxf(e, LRELU_SLOPE * e);
                float p = (jj[k] < cnt) ? __expf(e) : 0.f;
                a0c = fmaf(p, (float)v[k][0], a0c);
                a1c = fmaf(p, (float)v[k][1], a1c);
                a2c = fmaf(p, (float)v[k][2], a2c);
                a3c = fmaf(p, (float)v[k][3], a3c);
                s += p;
            }
        }
    }
    a0c += __shfl_xor(a0c, 32, 64);
    a1c += __shfl_xor(a1c, 32, 64);
    a2c += __shfl_xor(a2c, 32, 64);
    a3c += __shfl_xor(a3c, 32, 64);
    s   += __shfl_xor(s, 32, 64);
    float ps = 0.f, pd = 0.f;
    if (half == 0) {
        float inv = 1.f / (s + 1e-16f);
        float4 bb = ((const float4*)b1)[m];
        float o0 = fmaxf(fmaf(a0c, inv, bb.x), 0.f);  // relu between layers
        float o1 = fmaxf(fmaf(a1c, inv, bb.y), 0.f);
        float o2 = fmaxf(fmaf(a2c, inv, bb.z), 0.f);
        float o3 = fmaxf(fmaf(a3c, inv, bb.w), 0.f);
        f16x4 o;
        o[0] = (_Float16)o0; o[1] = (_Float16)o1;
        o[2] = (_Float16)o2; o[3] = (_Float16)o3;
        ((f16x4*)out)[node * 32 + m] = o;
        float4 w2s = ((const float4*)wa2)[m];
        float4 w2d = ((const float4*)(wa2 + 128))[m];
        ps = o0 * w2s.x + o1 * w2s.y + o2 * w2s.z + o3 * w2s.w;
        pd = o0 * w2d.x + o1 * w2d.y + o2 * w2d.z + o3 * w2d.w;
    }
#pragma unroll
    for (int o = 1; o <= 16; o <<= 1) {
        ps += __shfl_xor(ps, o, 64);
        pd += __shfl_xor(pd, o, 64);
    }
    if (lane == 0) {
        asrc2[node] = ps;
        adst2[node] = pd;
    }
}

// layer 2: one wave per dst node, direct-col layout. lane = {eslot(3b), sub(3b)}.
__global__ __launch_bounds__(256) void agg2_kernel(const __half* __restrict__ h2bh,
                                                   const float* __restrict__ asrc,
                                                   const float* __restrict__ adst,
                                                   const int* __restrict__ row_ptr,
                                                   const unsigned short* __restrict__ col,
                                                   const float* __restrict__ b2,
                                                   float* __restrict__ out, int n) {
    int wave = threadIdx.x >> 6;
    int lane = threadIdx.x & 63;
    int node = blockIdx.x * 4 + wave;
    if (node >= n) return;
    int eslot = lane >> 3;         // 8 edge slots
    int sub = lane & 7;            // 8 x f16x8 chunks = 64 ch
    const char* __restrict__ h2c = (const char*)h2bh;
    unsigned coff = (unsigned)sub << 4;   // byte offset of lane's 16B chunk (<128)
    float ad = adst[node];
    int start = row_ptr[node], end = row_ptr[node + 1];
    float acc[8];
#pragma unroll
    for (int c = 0; c < 8; ++c) acc[c] = 0.f;
    float s = 0.f;
    for (int base = start; base < end; base += 16) {
        // issue phase: 2 edge-groups
        int iA = base + eslot;
        int iB = iA + 8;
        int sA = (int)col[min(iA, end - 1)];
        int sB = (int)col[min(iB, end - 1)];
        f16x8 vA = *(const f16x8*)(h2c + ((((unsigned)sA) << 7) | coff));
        f16x8 vB = *(const f16x8*)(h2c + ((((unsigned)sB) << 7) | coff));
        float eA = asrc[sA] + ad;
        float eB = asrc[sB] + ad;
        // consume phase
        eA = fmaxf(eA, LRELU_SLOPE * eA);
        eB = fmaxf(eB, LRELU_SLOPE * eB);
        float pA = (iA < end) ? __expf(eA) : 0.f;
        float pB = (iB < end) ? __expf(eB) : 0.f;
#pragma unroll
        for (int c = 0; c < 8; ++c) acc[c] = fmaf(pA, (float)vA[c], acc[c]);
#pragma unroll
        for (int c = 0; c < 8; ++c) acc[c] = fmaf(pB, (float)vB[c], acc[c]);
        s += pA + pB;
    }
    // reduce across the 8 edge slots (strides 8..32); sub axis untouched
#pragma unroll
    for (int o = 8; o < 64; o <<= 1) {
#pragma unroll
        for (int c = 0; c < 8; ++c) acc[c] += __shfl_xor(acc[c], o, 64);
        s += __shfl_xor(s, o, 64);
    }
    if (lane < 8) {  // eslot == 0 lanes hold the 8 chunks
        float inv = 1.f / (s + 1e-16f);
        float4 bb0 = ((const float4*)b2)[sub * 2];
        float4 bb1 = ((const float4*)b2)[sub * 2 + 1];
        float4 o0, o1;
        o0.x = fmaf(acc[0], inv, bb0.x);
        o0.y = fmaf(acc[1], inv, bb0.y);
        o0.z = fmaf(acc[2], inv, bb0.z);
        o0.w = fmaf(acc[3], inv, bb0.w);
        o1.x = fmaf(acc[4], inv, bb1.x);
        o1.y = fmaf(acc[5], inv, bb1.y);
        o1.z = fmaf(acc[6], inv, bb1.z);
        o1.w = fmaf(acc[7], inv, bb1.w);
        ((float4*)(out + (size_t)node * 64))[sub * 2] = o0;
        ((float4*)(out + (size_t)node * 64))[sub * 2 + 1] = o1;
    }
}

// ---------------- launch ----------------

extern "C" void kernel_launch(void* const* d_in, const int* in_sizes, int n_in,
                              void* d_out, int out_size, void* d_ws, size_t ws_size,
                              hipStream_t stream) {
    const float* x      = (const float*)d_in[0];
    const int*   ei     = (const int*)d_in[1];
    const float* W1     = (const float*)d_in[2];
    const float* a_src1 = (const float*)d_in[3];
    const float* a_dst1 = (const float*)d_in[4];
    const float* b1     = (const float*)d_in[5];
    const float* W2     = (const float*)d_in[6];
    const float* a_src2 = (const float*)d_in[7];
    const float* a_dst2 = (const float*)d_in[8];
    const float* b2     = (const float*)d_in[9];
    float* out = (float*)d_out;

    const int N = in_sizes[0] / 128;
    const int E = in_sizes[1] / 2;
    const int total = E + N;
    const int nBuckets = (N + 255) >> 8;   // 196

    char* ws = (char*)d_ws;
    size_t off = 0;
    auto alloc = [&](size_t bytes) {
        void* p = ws + off;
        off += (bytes + 255) & ~(size_t)255;
        return p;
    };
    // Region A: records (CSR build), then h2in fp16 (agg1->gemm2).
    float* regionA = (float*)alloc((size_t)N * 128 * 4);
    __half* h1h   = (__half*)alloc((size_t)N * 128 * 2);
    __half* h2bh  = (__half*)alloc((size_t)N * 64 * 2);
    float* asrc1  = (float*)alloc((size_t)N * 4 * 4);
    float* adst1  = (float*)alloc((size_t)N * 4 * 4);
    float* asrc2  = (float*)alloc((size_t)N * 4);
    float* adst2  = (float*)alloc((size_t)N * 4);
    int*   row_ptr= (int*)alloc((size_t)(N + 1) * 4);
    int*   gfill  = (int*)alloc((size_t)nBuckets * 4);
    int*   bsums  = (int*)alloc((size_t)nBuckets * 4);
    float* wa2    = (float*)alloc(256 * 4);
    unsigned short* col = (unsigned short*)alloc((size_t)total * 2);

    unsigned int* records = (unsigned int*)regionA;          // 13.1MB
    __half* h2in = (__half*)regionA;                         // after CSR build done
    (void)ws_size; (void)n_in; (void)out_size;

    const int* ei_src = ei;
    const int* ei_dst = ei + E;

    const int chunk = (E + NBLK - 1) / NBLK;
    const int G1B = (N + 63) / 64;     // 782
    const int ALB = (N + 255) / 256;   // 196

    hipMemsetAsync(gfill, 0, (size_t)nBuckets * 4, stream);

    // K1: scatter || gemm1 || alpha1 || wa2
    k1_kernel<<<NBLK + G1B + ALB + 1, 256, 0, stream>>>(
        ei_src, ei_dst, records, gfill,
        x, W1, h1h, a_src1, a_dst1, asrc1, adst1,
        W2, a_src2, a_dst2, wa2,
        E, chunk, N, G1B, ALB);

    scan_blocksums_kernel<<<1, 256, 0, stream>>>(gfill, bsums, row_ptr, nBuckets, N, total);
    csr_fused_kernel<<<nBuckets, 256, 0, stream>>>(records, gfill, bsums, row_ptr, col, N);

    agg1_kernel<<<(N + 3) / 4, 256, 0, stream>>>(h1h, asrc1, adst1,
                                                 row_ptr, col, b1, wa2,
                                                 h2in, asrc2, adst2, N);

    gemm2_mfma_kernel<<<(N + 63) / 64, 256, 0, stream>>>(h2in, W2, h2bh, N);
    agg2_kernel<<<(N + 3) / 4, 256, 0, stream>>>(h2bh, asrc2, adst2,
                                                 row_ptr, col, b2, out, N);
}

// Round 6
// 240.045 us; speedup vs baseline: 1.6267x; 1.0089x over previous
//
#include <hip/hip_runtime.h>
#include <hip/hip_bf16.h>
#include <hip/hip_fp16.h>

// ---------------------------------------------------------------------------
// 2-layer GAT, N=50000, E=1.6M (+N self loops).
// R15 pipeline (6 dispatches):
//   memset(gfill) -> K1 [LDS-sorted scatter || gemm1-MFMA || alpha1 fp32 ||
//   wa2 build] -> csr_fused(inline prefix) -> agg1(+fused alpha2) ->
//   gemm2(pure) -> agg2.
// Key facts carried forward:
//  - agg1 @57us/172MB is the random-64B-line L2-miss ceiling (R11 probe:
//    3x MLP = +7%; R12 channel-slicing = 3.8x WORSE). Leave it.
//  - alphas as fp32 mini-GEMMs (R14) — epilogues gone from both GEMMs.
//  - R15: K1 scatter role was issuing E bucket-random 4B stores (~RFO
//    E x 128B ~ 200MB effective on the 3.4TB/s random path). Now: stage
//    records in LDS, per-block counting sort, coalesced 64B-run flush.
//    ei read once. scan_blocksums fused into csr_fused (196-elem reduce).
// ---------------------------------------------------------------------------

#define LRELU_SLOPE 0.2f
#define NBMAX 200        // max dst buckets (N <= 51200)
#define NBLK  512        // blocks in scatter role
#define BCAP  16384      // per-bucket record capacity (mean ~8163)
#define CAPIMG 16384     // csr_fused LDS image entries
#define SCAP  3328       // scatter stage capacity (chunk <= 3328)

typedef _Float16 f16x8 __attribute__((ext_vector_type(8)));
typedef _Float16 f16x4 __attribute__((ext_vector_type(4)));
typedef float f32x4 __attribute__((ext_vector_type(4)));

// ---------------- K1: scatter || gemm1 || alpha1 || wa2 ----------------
// Roles by blockIdx.x:
//   [0, NBLK)                : LDS counting-sort scatter of edge records
//   [NBLK, NBLK+G1B)         : gemm1 MFMA (X fp32 [n,128] @ W1 -> h1h fp16)
//   [NBLK+G1B, NBLK+G1B+ALB) : alpha1 = X @ [W1.a_src1 | W1.a_dst1] (fp32)
//   [NBLK+G1B+ALB]           : wa2 = [W2.a_src2 | W2.a_dst2] (256 floats)

__global__ __launch_bounds__(256) void k1_kernel(
    const int* __restrict__ ei_src, const int* __restrict__ ei_dst,
    unsigned int* __restrict__ records, int* __restrict__ gfill,
    const float* __restrict__ X, const float* __restrict__ W1,
    __half* __restrict__ h1h,
    const float* __restrict__ a_src1, const float* __restrict__ a_dst1,
    float* __restrict__ asrc1, float* __restrict__ adst1,
    const float* __restrict__ W2,
    const float* __restrict__ a_src2, const float* __restrict__ a_dst2,
    float* __restrict__ wa2,
    int E, int chunk, int N, int G1B, int ALB) {
    __shared__ __align__(16) char smem[34816];
    int t = threadIdx.x;
    int bid = blockIdx.x;

    if (bid < NBLK) {
        // ---------------- scatter role: LDS counting sort ----------------
        int* hist   = (int*)smem;            // [256] counts -> excl scan
        int* base_g = hist + 256;            // [256] global ticket base
        int* cur    = base_g + 256;          // [256] running fill
        int* sbuf   = cur + 256;             // [2][256] scan double-buffer
        unsigned int* ustage = (unsigned int*)(sbuf + 512);  // [SCAP]
        unsigned int* sstage = ustage + SCAP;                // [SCAP]

        hist[t] = 0;
        __syncthreads();
        int begin = bid * chunk;
        int endE = min(E, begin + chunk);
        int nE = endE - begin;
        for (int i = t; i < nE; i += 256) {
            int s = ei_src[begin + i], d = ei_dst[begin + i];
            unsigned int rec = (unsigned int)d | ((unsigned int)s << 16);
            ustage[i] = rec;
            atomicAdd(&hist[d >> 8], 1);
        }
        __syncthreads();
        int h = hist[t];
        if (t < NBMAX && h) base_g[t] = atomicAdd(&gfill[t], h);
        // exclusive scan of hist over 256 entries
        sbuf[t] = h;
        __syncthreads();
        int pi = 0;
#pragma unroll
        for (int off = 1; off < 256; off <<= 1) {
            int v = sbuf[pi * 256 + t];
            if (t >= off) v += sbuf[pi * 256 + t - off];
            sbuf[(pi ^ 1) * 256 + t] = v;
            __syncthreads();
            pi ^= 1;
        }
        int excl = sbuf[pi * 256 + t] - h;
        hist[t] = excl;   // repurpose hist as exclusive scan
        cur[t] = excl;
        __syncthreads();
        // sort into sstage
        for (int i = t; i < nE; i += 256) {
            unsigned int rec = ustage[i];
            int bkt = (rec & 0xFFFF) >> 8;
            int r = atomicAdd(&cur[bkt], 1);
            sstage[r] = rec;
        }
        __syncthreads();
        // coalesced flush: consecutive lanes write consecutive addresses
        // within each bucket run (avg run ~ 16 recs = 64B)
        for (int i = t; i < nE; i += 256) {
            unsigned int rec = sstage[i];
            int bkt = (rec & 0xFFFF) >> 8;
            int g = base_g[bkt] + (i - hist[bkt]);
            records[(size_t)bkt * BCAP + g] = rec;
        }
        return;
    }

    if (bid < NBLK + G1B) {
        // ---------------- gemm1 role (no alpha epilogue) ----------------
        constexpr int KP = 136;
        _Float16* wlds = (_Float16*)smem;  // wlds[n][k] = W1[k][n], 128xKP
        int gb = bid - NBLK;
        int wv = t >> 6, lane = t & 63;
        int quad = lane >> 4, m16 = lane & 15;
        for (int i = t; i < 4096; i += 256) {  // 128*128/4
            int k = i >> 5;
            int n0 = (i & 31) << 2;
            float4 v = *(const float4*)(W1 + k * 128 + n0);
            wlds[(n0 + 0) * KP + k] = (_Float16)v.x;
            wlds[(n0 + 1) * KP + k] = (_Float16)v.y;
            wlds[(n0 + 2) * KP + k] = (_Float16)v.z;
            wlds[(n0 + 3) * KP + k] = (_Float16)v.w;
        }
        __syncthreads();

        int row = gb * 64 + wv * 16 + m16;
        int rowC = min(row, N - 1);
        const float* xp = X + (size_t)rowC * 128;

        f32x4 acc[8];
#pragma unroll
        for (int nt = 0; nt < 8; ++nt) acc[nt] = (f32x4)0.f;

        for (int kt = 0; kt < 128; kt += 32) {
            float4 v0 = *(const float4*)(xp + kt + quad * 8);
            float4 v1 = *(const float4*)(xp + kt + quad * 8 + 4);
            f16x8 af;
            af[0] = (_Float16)v0.x; af[1] = (_Float16)v0.y;
            af[2] = (_Float16)v0.z; af[3] = (_Float16)v0.w;
            af[4] = (_Float16)v1.x; af[5] = (_Float16)v1.y;
            af[6] = (_Float16)v1.z; af[7] = (_Float16)v1.w;
#pragma unroll
            for (int nt = 0; nt < 8; ++nt) {
                f16x8 bf = *(const f16x8*)(&wlds[(nt * 16 + m16) * KP + kt + quad * 8]);
                acc[nt] = __builtin_amdgcn_mfma_f32_16x16x32_f16(af, bf, acc[nt], 0, 0, 0);
            }
        }

        int rowBaseW = gb * 64 + wv * 16;
#pragma unroll
        for (int r = 0; r < 4; ++r) {
            int orow = rowBaseW + quad * 4 + r;
            if (orow < N) {
#pragma unroll
                for (int nt = 0; nt < 8; ++nt)
                    h1h[(size_t)orow * 128 + nt * 16 + m16] = __float2half(acc[nt][r]);
            }
        }
        return;
    }

    int aid = bid - NBLK - G1B;
    if (aid < ALB) {
        // ---------------- alpha1 role: [N,128] @ [128,8] fp32 ----------------
        float* waL = (float*)smem;  // [8][128]
        {
            int k = t >> 1, grp = t & 1;
            const float* wrow = W1 + k * 128;
            const float* abase = grp ? a_dst1 : a_src1;
#pragma unroll
            for (int h = 0; h < 4; ++h) {
                const float* av = abase + h * 32;
                const float* wr = wrow + h * 32;
                float acc = 0.f;
                for (int c = 0; c < 32; ++c) acc += wr[c] * av[c];
                waL[(grp * 4 + h) * 128 + k] = acc;
            }
        }
        __syncthreads();
        int row = aid * 256 + t;
        if (row < N) {
            const float4* x4 = (const float4*)(X + (size_t)row * 128);
            float p[8];
#pragma unroll
            for (int o = 0; o < 8; ++o) p[o] = 0.f;
            for (int k4 = 0; k4 < 32; ++k4) {
                float4 xv = x4[k4];
#pragma unroll
                for (int o = 0; o < 8; ++o) {
                    float4 wv = ((const float4*)(waL + o * 128))[k4];
                    p[o] += xv.x * wv.x + xv.y * wv.y + xv.z * wv.z + xv.w * wv.w;
                }
            }
            float4 ps = {p[0], p[1], p[2], p[3]};
            float4 pd = {p[4], p[5], p[6], p[7]};
            ((float4*)asrc1)[row] = ps;
            ((float4*)adst1)[row] = pd;
        }
        return;
    }

    // ---------------- wa2 build block ----------------
    if (t < 128) {
        const float* wr = W2 + t * 64;
        float acc = 0.f;
        for (int c = 0; c < 64; ++c) acc += wr[c] * a_src2[c];
        wa2[t] = acc;
    } else {
        int k = t - 128;
        const float* wr = W2 + k * 64;
        float acc = 0.f;
        for (int c = 0; c < 64; ++c) acc += wr[c] * a_dst2[c];
        wa2[128 + k] = acc;
    }
}

// ---------------- CSR finalize: fused prefix + degree + scan + scatter ----

__global__ __launch_bounds__(256) void csr_fused_kernel(const unsigned int* __restrict__ records,
                                                        const int* __restrict__ gfill,
                                                        int* __restrict__ row_ptr,
                                                        unsigned short* __restrict__ col,
                                                        int N, int total) {
    __shared__ unsigned short img[CAPIMG];
    __shared__ int cnt[2][256];
    __shared__ int lfill[256];
    __shared__ int rbuf[4];
    int t = threadIdx.x, b = blockIdx.x;
    int bBase = b << 8;
    int bEnd = min(bBase + 256, N);
    // inline prefix: rbase = sum_{i<b} gfill[i] + 256*b (buckets < b are full)
    int pv = (t < b) ? gfill[t] : 0;
#pragma unroll
    for (int o = 1; o < 64; o <<= 1) pv += __shfl_xor(pv, o, 64);
    if ((t & 63) == 0) rbuf[t >> 6] = pv;
    int c = gfill[b];
    int gi = bBase + t;
    cnt[0][t] = (gi < bEnd) ? 1 : 0;   // self loop counts
    if (b == 0 && t == 0) row_ptr[N] = total;
    __syncthreads();
    int rbase = rbuf[0] + rbuf[1] + rbuf[2] + rbuf[3] + (b << 8);
    int size = c + (bEnd - bBase);
    bool lds = (size <= CAPIMG);
    const unsigned int* r = records + (size_t)b * BCAP;
    for (int i = t; i < c; i += 256) atomicAdd(&cnt[0][r[i] & 255], 1);
    __syncthreads();
    int d = cnt[0][t];                 // this node's degree (incl self)
    int pi = 0;
#pragma unroll
    for (int off = 1; off < 256; off <<= 1) {
        int v = cnt[pi][t];
        if (t >= off) v += cnt[pi][t - off];
        cnt[pi ^ 1][t] = v;
        __syncthreads();
        pi ^= 1;
    }
    int local = cnt[pi][t] - d;        // exclusive prefix within bucket
    if (gi < bEnd) {
        row_ptr[gi] = rbase + local;
        lfill[t] = local + 1;          // slot 0 = self loop
        if (lds) img[local] = (unsigned short)gi;
        else col[rbase + local] = (unsigned short)gi;
    }
    __syncthreads();
    for (int i = t; i < c; i += 256) {
        unsigned int rec = r[i];
        int d8 = rec & 255;
        unsigned short s = (unsigned short)(rec >> 16);
        int p = atomicAdd(&lfill[d8], 1);
        if (lds) img[p] = s;
        else col[rbase + p] = s;
    }
    __syncthreads();
    if (lds) {
        for (int i = t; i < size; i += 256) col[rbase + i] = img[i];
    }
}

// ---------------- GEMM2: h2in fp16 [n,128] @ W2 [128,64] -> h2bh fp16 ----

__global__ __launch_bounds__(256) void gemm2_mfma_kernel(const __half* __restrict__ Xh,
                                                         const float* __restrict__ W,
                                                         __half* __restrict__ outh, int nrows) {
    constexpr int KP = 136;
    __shared__ _Float16 wlds[64 * KP];  // wlds[n][k] = W[k][n]
    int t = threadIdx.x;
    int wv = t >> 6, lane = t & 63;
    int quad = lane >> 4, m16 = lane & 15;
    for (int i = t; i < 2048; i += 256) {  // 128*64/4
        int k = i >> 4;
        int n0 = (i & 15) << 2;
        float4 v = *(const float4*)(W + k * 64 + n0);
        wlds[(n0 + 0) * KP + k] = (_Float16)v.x;
        wlds[(n0 + 1) * KP + k] = (_Float16)v.y;
        wlds[(n0 + 2) * KP + k] = (_Float16)v.z;
        wlds[(n0 + 3) * KP + k] = (_Float16)v.w;
    }
    __syncthreads();

    int row = blockIdx.x * 64 + wv * 16 + m16;
    int rowC = min(row, nrows - 1);
    const _Float16* xp = (const _Float16*)Xh + (size_t)rowC * 128;

    f32x4 acc[4];
#pragma unroll
    for (int nt = 0; nt < 4; ++nt) acc[nt] = (f32x4)0.f;

    for (int kt = 0; kt < 128; kt += 32) {
        f16x8 af = *(const f16x8*)(xp + kt + quad * 8);
#pragma unroll
        for (int nt = 0; nt < 4; ++nt) {
            f16x8 bf = *(const f16x8*)(&wlds[(nt * 16 + m16) * KP + kt + quad * 8]);
            acc[nt] = __builtin_amdgcn_mfma_f32_16x16x32_f16(af, bf, acc[nt], 0, 0, 0);
        }
    }

    int rowBaseW = blockIdx.x * 64 + wv * 16;
#pragma unroll
    for (int r = 0; r < 4; ++r) {
        int orow = rowBaseW + quad * 4 + r;
        if (orow < nrows) {
#pragma unroll
            for (int nt = 0; nt < 4; ++nt)
                outh[(size_t)orow * 64 + nt * 16 + m16] = __float2half(acc[nt][r]);
        }
    }
}

// ---------------- aggregation ----------------

// layer 1 (R11 form, at the random-line ceiling) + fused alpha2 epilogue.
__global__ __launch_bounds__(256) void agg1_kernel(const __half* __restrict__ h1h,
                                                   const float* __restrict__ asrc,
                                                   const float* __restrict__ adst,
                                                   const int* __restrict__ row_ptr,
                                                   const unsigned short* __restrict__ col,
                                                   const float* __restrict__ b1,
                                                   const float* __restrict__ wa2,
                                                   __half* __restrict__ out,
                                                   float* __restrict__ asrc2,
                                                   float* __restrict__ adst2, int n) {
    int wave = threadIdx.x >> 6;
    int lane = threadIdx.x & 63;
    int node = blockIdx.x * 4 + wave;
    if (node >= n) return;
    int half = lane >> 5;
    int m = lane & 31;             // f16x4 chunk index within 128-ch row
    int head = m >> 3;             // 4 heads x 8 chunks
    const char* __restrict__ h1c = (const char*)h1h;
    const char* __restrict__ asc = (const char*)asrc;
    unsigned moff = (unsigned)m << 3;    // byte offset of lane's 8B chunk (<256)
    unsigned aoff = (unsigned)head << 2; // byte offset into 16B asrc row
    float ad = adst[node * 4 + head];
    int start = row_ptr[node], end = row_ptr[node + 1];
    float a0c = 0.f, a1c = 0.f, a2c = 0.f, a3c = 0.f, s = 0.f;
    for (int base = start; base < end; base += 64) {
        int cnt = min(64, end - base);
        int idx = base + lane;
        int myS = (idx < end) ? (int)col[idx] : 0;
        for (int j = 0; j < cnt; j += 12) {
            // ---- issue phase: 6 row-gathers + 6 asrc gathers per lane ----
            int jj[6];
            int sv[6];
#pragma unroll
            for (int k = 0; k < 6; ++k) {
                jj[k] = j + 2 * k + half;          // >=64 wraps in shfl; guarded below
                sv[k] = __shfl(myS, jj[k], 64);
            }
            f16x4 v[6];
            float as[6];
#pragma unroll
            for (int k = 0; k < 6; ++k) {
                v[k]  = *(const f16x4*)(h1c + ((((unsigned)sv[k]) << 8) | moff));
                as[k] = *(const float*)(asc + ((((unsigned)sv[k]) << 4) | aoff));
            }
            // ---- consume phase ----
#pragma unroll
            for (int k = 0; k < 6; ++k) {
                float e = as[k] + ad;
                e = fmaxf(e, LRELU_SLOPE * e);
                float p = (jj[k] < cnt) ? __expf(e) : 0.f;
                a0c = fmaf(p, (float)v[k][0], a0c);
                a1c = fmaf(p, (float)v[k][1], a1c);
                a2c = fmaf(p, (float)v[k][2], a2c);
                a3c = fmaf(p, (float)v[k][3], a3c);
                s += p;
            }
        }
    }
    a0c += __shfl_xor(a0c, 32, 64);
    a1c += __shfl_xor(a1c, 32, 64);
    a2c += __shfl_xor(a2c, 32, 64);
    a3c += __shfl_xor(a3c, 32, 64);
    s   += __shfl_xor(s, 32, 64);
    float ps = 0.f, pd = 0.f;
    if (half == 0) {
        float inv = 1.f / (s + 1e-16f);
        float4 bb = ((const float4*)b1)[m];
        float o0 = fmaxf(fmaf(a0c, inv, bb.x), 0.f);  // relu between layers
        float o1 = fmaxf(fmaf(a1c, inv, bb.y), 0.f);
        float o2 = fmaxf(fmaf(a2c, inv, bb.z), 0.f);
        float o3 = fmaxf(fmaf(a3c, inv, bb.w), 0.f);
        f16x4 o;
        o[0] = (_Float16)o0; o[1] = (_Float16)o1;
        o[2] = (_Float16)o2; o[3] = (_Float16)o3;
        ((f16x4*)out)[node * 32 + m] = o;
        float4 w2s = ((const float4*)wa2)[m];
        float4 w2d = ((const float4*)(wa2 + 128))[m];
        ps = o0 * w2s.x + o1 * w2s.y + o2 * w2s.z + o3 * w2s.w;
        pd = o0 * w2d.x + o1 * w2d.y + o2 * w2d.z + o3 * w2d.w;
    }
#pragma unroll
    for (int o = 1; o <= 16; o <<= 1) {
        ps += __shfl_xor(ps, o, 64);
        pd += __shfl_xor(pd, o, 64);
    }
    if (lane == 0) {
        asrc2[node] = ps;
        adst2[node] = pd;
    }
}

// layer 2: one wave per dst node, direct-col layout. lane = {eslot(3b), sub(3b)}.
__global__ __launch_bounds__(256) void agg2_kernel(const __half* __restrict__ h2bh,
                                                   const float* __restrict__ asrc,
                                                   const float* __restrict__ adst,
                                                   const int* __restrict__ row_ptr,
                                                   const unsigned short* __restrict__ col,
                                                   const float* __restrict__ b2,
                                                   float* __restrict__ out, int n) {
    int wave = threadIdx.x >> 6;
    int lane = threadIdx.x & 63;
    int node = blockIdx.x * 4 + wave;
    if (node >= n) return;
    int eslot = lane >> 3;         // 8 edge slots
    int sub = lane & 7;            // 8 x f16x8 chunks = 64 ch
    const char* __restrict__ h2c = (const char*)h2bh;
    unsigned coff = (unsigned)sub << 4;   // byte offset of lane's 16B chunk (<128)
    float ad = adst[node];
    int start = row_ptr[node], end = row_ptr[node + 1];
    float acc[8];
#pragma unroll
    for (int c = 0; c < 8; ++c) acc[c] = 0.f;
    float s = 0.f;
    for (int base = start; base < end; base += 16) {
        // issue phase: 2 edge-groups
        int iA = base + eslot;
        int iB = iA + 8;
        int sA = (int)col[min(iA, end - 1)];
        int sB = (int)col[min(iB, end - 1)];
        f16x8 vA = *(const f16x8*)(h2c + ((((unsigned)sA) << 7) | coff));
        f16x8 vB = *(const f16x8*)(h2c + ((((unsigned)sB) << 7) | coff));
        float eA = asrc[sA] + ad;
        float eB = asrc[sB] + ad;
        // consume phase
        eA = fmaxf(eA, LRELU_SLOPE * eA);
        eB = fmaxf(eB, LRELU_SLOPE * eB);
        float pA = (iA < end) ? __expf(eA) : 0.f;
        float pB = (iB < end) ? __expf(eB) : 0.f;
#pragma unroll
        for (int c = 0; c < 8; ++c) acc[c] = fmaf(pA, (float)vA[c], acc[c]);
#pragma unroll
        for (int c = 0; c < 8; ++c) acc[c] = fmaf(pB, (float)vB[c], acc[c]);
        s += pA + pB;
    }
    // reduce across the 8 edge slots (strides 8..32); sub axis untouched
#pragma unroll
    for (int o = 8; o < 64; o <<= 1) {
#pragma unroll
        for (int c = 0; c < 8; ++c) acc[c] += __shfl_xor(acc[c], o, 64);
        s += __shfl_xor(s, o, 64);
    }
    if (lane < 8) {  // eslot == 0 lanes hold the 8 chunks
        float inv = 1.f / (s + 1e-16f);
        float4 bb0 = ((const float4*)b2)[sub * 2];
        float4 bb1 = ((const float4*)b2)[sub * 2 + 1];
        float4 o0, o1;
        o0.x = fmaf(acc[0], inv, bb0.x);
        o0.y = fmaf(acc[1], inv, bb0.y);
        o0.z = fmaf(acc[2], inv, bb0.z);
        o0.w = fmaf(acc[3], inv, bb0.w);
        o1.x = fmaf(acc[4], inv, bb1.x);
        o1.y = fmaf(acc[5], inv, bb1.y);
        o1.z = fmaf(acc[6], inv, bb1.z);
        o1.w = fmaf(acc[7], inv, bb1.w);
        ((float4*)(out + (size_t)node * 64))[sub * 2] = o0;
        ((float4*)(out + (size_t)node * 64))[sub * 2 + 1] = o1;
    }
}

// ---------------- launch ----------------

extern "C" void kernel_launch(void* const* d_in, const int* in_sizes, int n_in,
                              void* d_out, int out_size, void* d_ws, size_t ws_size,
                              hipStream_t stream) {
    const float* x      = (const float*)d_in[0];
    const int*   ei     = (const int*)d_in[1];
    const float* W1     = (const float*)d_in[2];
    const float* a_src1 = (const float*)d_in[3];
    const float* a_dst1 = (const float*)d_in[4];
    const float* b1     = (const float*)d_in[5];
    const float* W2     = (const float*)d_in[6];
    const float* a_src2 = (const float*)d_in[7];
    const float* a_dst2 = (const float*)d_in[8];
    const float* b2     = (const float*)d_in[9];
    float* out = (float*)d_out;

    const int N = in_sizes[0] / 128;
    const int E = in_sizes[1] / 2;
    const int total = E + N;
    const int nBuckets = (N + 255) >> 8;   // 196

    char* ws = (char*)d_ws;
    size_t off = 0;
    auto alloc = [&](size_t bytes) {
        void* p = ws + off;
        off += (bytes + 255) & ~(size_t)255;
        return p;
    };
    // Region A: records (CSR build), then h2in fp16 (agg1->gemm2).
    float* regionA = (float*)alloc((size_t)N * 128 * 4);
    __half* h1h   = (__half*)alloc((size_t)N * 128 * 2);
    __half* h2bh  = (__half*)alloc((size_t)N * 64 * 2);
    float* asrc1  = (float*)alloc((size_t)N * 4 * 4);
    float* adst1  = (float*)alloc((size_t)N * 4 * 4);
    float* asrc2  = (float*)alloc((size_t)N * 4);
    float* adst2  = (float*)alloc((size_t)N * 4);
    int*   row_ptr= (int*)alloc((size_t)(N + 1) * 4);
    int*   gfill  = (int*)alloc((size_t)nBuckets * 4);
    float* wa2    = (float*)alloc(256 * 4);
    unsigned short* col = (unsigned short*)alloc((size_t)total * 2);

    unsigned int* records = (unsigned int*)regionA;          // 13.1MB
    __half* h2in = (__half*)regionA;                         // after CSR build done
    (void)ws_size; (void)n_in; (void)out_size;

    const int* ei_src = ei;
    const int* ei_dst = ei + E;

    const int chunk = (E + NBLK - 1) / NBLK;   // 3125 <= SCAP
    const int G1B = (N + 63) / 64;     // 782
    const int ALB = (N + 255) / 256;   // 196

    hipMemsetAsync(gfill, 0, (size_t)nBuckets * 4, stream);

    // K1: scatter || gemm1 || alpha1 || wa2
    k1_kernel<<<NBLK + G1B + ALB + 1, 256, 0, stream>>>(
        ei_src, ei_dst, records, gfill,
        x, W1, h1h, a_src1, a_dst1, asrc1, adst1,
        W2, a_src2, a_dst2, wa2,
        E, chunk, N, G1B, ALB);

    csr_fused_kernel<<<nBuckets, 256, 0, stream>>>(records, gfill, row_ptr, col, N, total);

    agg1_kernel<<<(N + 3) / 4, 256, 0, stream>>>(h1h, asrc1, adst1,
                                                 row_ptr, col, b1, wa2,
                                                 h2in, asrc2, adst2, N);

    gemm2_mfma_kernel<<<(N + 63) / 64, 256, 0, stream>>>(h2in, W2, h2bh, N);
    agg2_kernel<<<(N + 3) / 4, 256, 0, stream>>>(h2bh, asrc2, adst2,
                                                 row_ptr, col, b2, out, N);
}

// Round 7
// 223.911 us; speedup vs baseline: 1.7439x; 1.0721x over previous
//
#include <hip/hip_runtime.h>
#include <hip/hip_bf16.h>
#include <hip/hip_fp16.h>

// ---------------------------------------------------------------------------
// 2-layer GAT, N=50000, E=1.6M (+N self loops).
// R16 pipeline (6 dispatches):
//   memset(gfill) -> K1 [LDS-sorted scatter || gemm1-MFMA || alpha1 fp32 ||
//   wa2 build] -> csr_fused(1024thr, inline prefix) -> agg1(+fused alpha2) ->
//   gemm2(pure) -> agg2(24-edge batches).
// Key facts carried forward:
//  - agg1 @58us/172MB is the random-64B-line L2-miss ceiling (R11 probe:
//    3x MLP = +7%; R12 channel-slicing = 3.8x WORSE). Leave it.
//  - alphas as fp32 mini-GEMMs (R14) — epilogues gone from both GEMMs.
//  - R15 scatter coalescing: only -2us. R16 theory: csr_fused at 196x256
//    (<1 block/CU, ~33 serial iters/pass) is the hidden cost -> 1024 thr.
// ---------------------------------------------------------------------------

#define LRELU_SLOPE 0.2f
#define NBMAX 200        // max dst buckets (N <= 51200)
#define NBLK  512        // blocks in scatter role
#define BCAP  16384      // per-bucket record capacity (mean ~8163)
#define CAPIMG 16384     // csr_fused LDS image entries
#define SCAP  3328       // scatter stage capacity (chunk <= 3328)

typedef _Float16 f16x8 __attribute__((ext_vector_type(8)));
typedef _Float16 f16x4 __attribute__((ext_vector_type(4)));
typedef float f32x4 __attribute__((ext_vector_type(4)));

// ---------------- K1: scatter || gemm1 || alpha1 || wa2 ----------------
// Roles by blockIdx.x:
//   [0, NBLK)                : LDS counting-sort scatter of edge records
//   [NBLK, NBLK+G1B)         : gemm1 MFMA (X fp32 [n,128] @ W1 -> h1h fp16)
//   [NBLK+G1B, NBLK+G1B+ALB) : alpha1 = X @ [W1.a_src1 | W1.a_dst1] (fp32)
//   [NBLK+G1B+ALB]           : wa2 = [W2.a_src2 | W2.a_dst2] (256 floats)

__global__ __launch_bounds__(256) void k1_kernel(
    const int* __restrict__ ei_src, const int* __restrict__ ei_dst,
    unsigned int* __restrict__ records, int* __restrict__ gfill,
    const float* __restrict__ X, const float* __restrict__ W1,
    __half* __restrict__ h1h,
    const float* __restrict__ a_src1, const float* __restrict__ a_dst1,
    float* __restrict__ asrc1, float* __restrict__ adst1,
    const float* __restrict__ W2,
    const float* __restrict__ a_src2, const float* __restrict__ a_dst2,
    float* __restrict__ wa2,
    int E, int chunk, int N, int G1B, int ALB) {
    __shared__ __align__(16) char smem[34816];
    int t = threadIdx.x;
    int bid = blockIdx.x;

    if (bid < NBLK) {
        // ---------------- scatter role: LDS counting sort ----------------
        int* hist   = (int*)smem;            // [256] counts -> excl scan
        int* base_g = hist + 256;            // [256] global ticket base
        int* cur    = base_g + 256;          // [256] running fill
        int* sbuf   = cur + 256;             // [2][256] scan double-buffer
        unsigned int* ustage = (unsigned int*)(sbuf + 512);  // [SCAP]
        unsigned int* sstage = ustage + SCAP;                // [SCAP]

        hist[t] = 0;
        __syncthreads();
        int begin = bid * chunk;
        int endE = min(E, begin + chunk);
        int nE = endE - begin;
        for (int i = t; i < nE; i += 256) {
            int s = ei_src[begin + i], d = ei_dst[begin + i];
            unsigned int rec = (unsigned int)d | ((unsigned int)s << 16);
            ustage[i] = rec;
            atomicAdd(&hist[d >> 8], 1);
        }
        __syncthreads();
        int h = hist[t];
        if (t < NBMAX && h) base_g[t] = atomicAdd(&gfill[t], h);
        // exclusive scan of hist over 256 entries
        sbuf[t] = h;
        __syncthreads();
        int pi = 0;
#pragma unroll
        for (int off = 1; off < 256; off <<= 1) {
            int v = sbuf[pi * 256 + t];
            if (t >= off) v += sbuf[pi * 256 + t - off];
            sbuf[(pi ^ 1) * 256 + t] = v;
            __syncthreads();
            pi ^= 1;
        }
        int excl = sbuf[pi * 256 + t] - h;
        hist[t] = excl;   // repurpose hist as exclusive scan
        cur[t] = excl;
        __syncthreads();
        // sort into sstage
        for (int i = t; i < nE; i += 256) {
            unsigned int rec = ustage[i];
            int bkt = (rec & 0xFFFF) >> 8;
            int r = atomicAdd(&cur[bkt], 1);
            sstage[r] = rec;
        }
        __syncthreads();
        // coalesced flush: consecutive lanes write consecutive addresses
        // within each bucket run (avg run ~ 16 recs = 64B)
        for (int i = t; i < nE; i += 256) {
            unsigned int rec = sstage[i];
            int bkt = (rec & 0xFFFF) >> 8;
            int g = base_g[bkt] + (i - hist[bkt]);
            records[(size_t)bkt * BCAP + g] = rec;
        }
        return;
    }

    if (bid < NBLK + G1B) {
        // ---------------- gemm1 role (no alpha epilogue) ----------------
        constexpr int KP = 136;
        _Float16* wlds = (_Float16*)smem;  // wlds[n][k] = W1[k][n], 128xKP
        int gb = bid - NBLK;
        int wv = t >> 6, lane = t & 63;
        int quad = lane >> 4, m16 = lane & 15;
        for (int i = t; i < 4096; i += 256) {  // 128*128/4
            int k = i >> 5;
            int n0 = (i & 31) << 2;
            float4 v = *(const float4*)(W1 + k * 128 + n0);
            wlds[(n0 + 0) * KP + k] = (_Float16)v.x;
            wlds[(n0 + 1) * KP + k] = (_Float16)v.y;
            wlds[(n0 + 2) * KP + k] = (_Float16)v.z;
            wlds[(n0 + 3) * KP + k] = (_Float16)v.w;
        }
        __syncthreads();

        int row = gb * 64 + wv * 16 + m16;
        int rowC = min(row, N - 1);
        const float* xp = X + (size_t)rowC * 128;

        f32x4 acc[8];
#pragma unroll
        for (int nt = 0; nt < 8; ++nt) acc[nt] = (f32x4)0.f;

        for (int kt = 0; kt < 128; kt += 32) {
            float4 v0 = *(const float4*)(xp + kt + quad * 8);
            float4 v1 = *(const float4*)(xp + kt + quad * 8 + 4);
            f16x8 af;
            af[0] = (_Float16)v0.x; af[1] = (_Float16)v0.y;
            af[2] = (_Float16)v0.z; af[3] = (_Float16)v0.w;
            af[4] = (_Float16)v1.x; af[5] = (_Float16)v1.y;
            af[6] = (_Float16)v1.z; af[7] = (_Float16)v1.w;
#pragma unroll
            for (int nt = 0; nt < 8; ++nt) {
                f16x8 bf = *(const f16x8*)(&wlds[(nt * 16 + m16) * KP + kt + quad * 8]);
                acc[nt] = __builtin_amdgcn_mfma_f32_16x16x32_f16(af, bf, acc[nt], 0, 0, 0);
            }
        }

        int rowBaseW = gb * 64 + wv * 16;
#pragma unroll
        for (int r = 0; r < 4; ++r) {
            int orow = rowBaseW + quad * 4 + r;
            if (orow < N) {
#pragma unroll
                for (int nt = 0; nt < 8; ++nt)
                    h1h[(size_t)orow * 128 + nt * 16 + m16] = __float2half(acc[nt][r]);
            }
        }
        return;
    }

    int aid = bid - NBLK - G1B;
    if (aid < ALB) {
        // ---------------- alpha1 role: [N,128] @ [128,8] fp32 ----------------
        float* waL = (float*)smem;  // [8][128]
        {
            int k = t >> 1, grp = t & 1;
            const float* wrow = W1 + k * 128;
            const float* abase = grp ? a_dst1 : a_src1;
#pragma unroll
            for (int h = 0; h < 4; ++h) {
                const float* av = abase + h * 32;
                const float* wr = wrow + h * 32;
                float acc = 0.f;
                for (int c = 0; c < 32; ++c) acc += wr[c] * av[c];
                waL[(grp * 4 + h) * 128 + k] = acc;
            }
        }
        __syncthreads();
        int row = aid * 256 + t;
        if (row < N) {
            const float4* x4 = (const float4*)(X + (size_t)row * 128);
            float p[8];
#pragma unroll
            for (int o = 0; o < 8; ++o) p[o] = 0.f;
            for (int k4 = 0; k4 < 32; ++k4) {
                float4 xv = x4[k4];
#pragma unroll
                for (int o = 0; o < 8; ++o) {
                    float4 wv = ((const float4*)(waL + o * 128))[k4];
                    p[o] += xv.x * wv.x + xv.y * wv.y + xv.z * wv.z + xv.w * wv.w;
                }
            }
            float4 ps = {p[0], p[1], p[2], p[3]};
            float4 pd = {p[4], p[5], p[6], p[7]};
            ((float4*)asrc1)[row] = ps;
            ((float4*)adst1)[row] = pd;
        }
        return;
    }

    // ---------------- wa2 build block ----------------
    if (t < 128) {
        const float* wr = W2 + t * 64;
        float acc = 0.f;
        for (int c = 0; c < 64; ++c) acc += wr[c] * a_src2[c];
        wa2[t] = acc;
    } else {
        int k = t - 128;
        const float* wr = W2 + k * 64;
        float acc = 0.f;
        for (int c = 0; c < 64; ++c) acc += wr[c] * a_dst2[c];
        wa2[128 + k] = acc;
    }
}

// ---------------- CSR finalize: fused prefix + degree + scan + scatter ----
// R16: 1024 threads/block (was 256 — <1 block/CU with ~33 serial iters/pass).

__global__ __launch_bounds__(1024) void csr_fused_kernel(const unsigned int* __restrict__ records,
                                                         const int* __restrict__ gfill,
                                                         int* __restrict__ row_ptr,
                                                         unsigned short* __restrict__ col,
                                                         int N, int total) {
    __shared__ unsigned short img[CAPIMG];
    __shared__ int cnt[2][256];
    __shared__ int lfill[256];
    __shared__ int rbuf[4];
    int t = threadIdx.x, b = blockIdx.x;
    int bBase = b << 8;
    int bEnd = min(bBase + 256, N);
    int gi = bBase + t;
    // inline prefix: rbase = sum_{i<b} gfill[i] + 256*b (buckets < b are full)
    if (t < 256) {
        int pv = (t < b) ? gfill[t] : 0;
#pragma unroll
        for (int o = 1; o < 64; o <<= 1) pv += __shfl_xor(pv, o, 64);
        if ((t & 63) == 0) rbuf[t >> 6] = pv;
        cnt[0][t] = (gi < bEnd) ? 1 : 0;   // self loop counts
    }
    if (b == 0 && t == 0) row_ptr[N] = total;
    int c = gfill[b];
    __syncthreads();
    int rbase = rbuf[0] + rbuf[1] + rbuf[2] + rbuf[3] + (b << 8);
    int size = c + (bEnd - bBase);
    bool lds = (size <= CAPIMG);
    const unsigned int* r = records + (size_t)b * BCAP;
    for (int i = t; i < c; i += 1024) atomicAdd(&cnt[0][r[i] & 255], 1);
    __syncthreads();
    int d = (t < 256) ? cnt[0][t] : 0;  // node degree (incl self)
    int pi = 0;
#pragma unroll
    for (int off = 1; off < 256; off <<= 1) {
        if (t < 256) {
            int v = cnt[pi][t];
            if (t >= off) v += cnt[pi][t - off];
            cnt[pi ^ 1][t] = v;
        }
        __syncthreads();
        pi ^= 1;
    }
    if (t < 256) {
        int local = cnt[pi][t] - d;    // exclusive prefix within bucket
        if (gi < bEnd) {
            row_ptr[gi] = rbase + local;
            lfill[t] = local + 1;      // slot 0 = self loop
            if (lds) img[local] = (unsigned short)gi;
            else col[rbase + local] = (unsigned short)gi;
        }
    }
    __syncthreads();
    for (int i = t; i < c; i += 1024) {
        unsigned int rec = r[i];
        int d8 = rec & 255;
        unsigned short s = (unsigned short)(rec >> 16);
        int p = atomicAdd(&lfill[d8], 1);
        if (lds) img[p] = s;
        else col[rbase + p] = s;
    }
    __syncthreads();
    if (lds) {
        for (int i = t; i < size; i += 1024) col[rbase + i] = img[i];
    }
}

// ---------------- GEMM2: h2in fp16 [n,128] @ W2 [128,64] -> h2bh fp16 ----

__global__ __launch_bounds__(256) void gemm2_mfma_kernel(const __half* __restrict__ Xh,
                                                         const float* __restrict__ W,
                                                         __half* __restrict__ outh, int nrows) {
    constexpr int KP = 136;
    __shared__ _Float16 wlds[64 * KP];  // wlds[n][k] = W[k][n]
    int t = threadIdx.x;
    int wv = t >> 6, lane = t & 63;
    int quad = lane >> 4, m16 = lane & 15;
    for (int i = t; i < 2048; i += 256) {  // 128*64/4
        int k = i >> 4;
        int n0 = (i & 15) << 2;
        float4 v = *(const float4*)(W + k * 64 + n0);
        wlds[(n0 + 0) * KP + k] = (_Float16)v.x;
        wlds[(n0 + 1) * KP + k] = (_Float16)v.y;
        wlds[(n0 + 2) * KP + k] = (_Float16)v.z;
        wlds[(n0 + 3) * KP + k] = (_Float16)v.w;
    }
    __syncthreads();

    int row = blockIdx.x * 64 + wv * 16 + m16;
    int rowC = min(row, nrows - 1);
    const _Float16* xp = (const _Float16*)Xh + (size_t)rowC * 128;

    f32x4 acc[4];
#pragma unroll
    for (int nt = 0; nt < 4; ++nt) acc[nt] = (f32x4)0.f;

    for (int kt = 0; kt < 128; kt += 32) {
        f16x8 af = *(const f16x8*)(xp + kt + quad * 8);
#pragma unroll
        for (int nt = 0; nt < 4; ++nt) {
            f16x8 bf = *(const f16x8*)(&wlds[(nt * 16 + m16) * KP + kt + quad * 8]);
            acc[nt] = __builtin_amdgcn_mfma_f32_16x16x32_f16(af, bf, acc[nt], 0, 0, 0);
        }
    }

    int rowBaseW = blockIdx.x * 64 + wv * 16;
#pragma unroll
    for (int r = 0; r < 4; ++r) {
        int orow = rowBaseW + quad * 4 + r;
        if (orow < nrows) {
#pragma unroll
            for (int nt = 0; nt < 4; ++nt)
                outh[(size_t)orow * 64 + nt * 16 + m16] = __float2half(acc[nt][r]);
        }
    }
}

// ---------------- aggregation ----------------

// layer 1 (R11 form, at the random-line ceiling) + fused alpha2 epilogue.
__global__ __launch_bounds__(256) void agg1_kernel(const __half* __restrict__ h1h,
                                                   const float* __restrict__ asrc,
                                                   const float* __restrict__ adst,
                                                   const int* __restrict__ row_ptr,
                                                   const unsigned short* __restrict__ col,
                                                   const float* __restrict__ b1,
                                                   const float* __restrict__ wa2,
                                                   __half* __restrict__ out,
                                                   float* __restrict__ asrc2,
                                                   float* __restrict__ adst2, int n) {
    int wave = threadIdx.x >> 6;
    int lane = threadIdx.x & 63;
    int node = blockIdx.x * 4 + wave;
    if (node >= n) return;
    int half = lane >> 5;
    int m = lane & 31;             // f16x4 chunk index within 128-ch row
    int head = m >> 3;             // 4 heads x 8 chunks
    const char* __restrict__ h1c = (const char*)h1h;
    const char* __restrict__ asc = (const char*)asrc;
    unsigned moff = (unsigned)m << 3;    // byte offset of lane's 8B chunk (<256)
    unsigned aoff = (unsigned)head << 2; // byte offset into 16B asrc row
    float ad = adst[node * 4 + head];
    int start = row_ptr[node], end = row_ptr[node + 1];
    float a0c = 0.f, a1c = 0.f, a2c = 0.f, a3c = 0.f, s = 0.f;
    for (int base = start; base < end; base += 64) {
        int cnt = min(64, end - base);
        int idx = base + lane;
        int myS = (idx < end) ? (int)col[idx] : 0;
        for (int j = 0; j < cnt; j += 12) {
            // ---- issue phase: 6 row-gathers + 6 asrc gathers per lane ----
            int jj[6];
            int sv[6];
#pragma unroll
            for (int k = 0; k < 6; ++k) {
                jj[k] = j + 2 * k + half;          // >=64 wraps in shfl; guarded below
                sv[k] = __shfl(myS, jj[k], 64);
            }
            f16x4 v[6];
            float as[6];
#pragma unroll
            for (int k = 0; k < 6; ++k) {
                v[k]  = *(const f16x4*)(h1c + ((((unsigned)sv[k]) << 8) | moff));
                as[k] = *(const float*)(asc + ((((unsigned)sv[k]) << 4) | aoff));
            }
            // ---- consume phase ----
#pragma unroll
            for (int k = 0; k < 6; ++k) {
                float e = as[k] + ad;
                e = fmaxf(e, LRELU_SLOPE * e);
                float p = (jj[k] < cnt) ? __expf(e) : 0.f;
                a0c = fmaf(p, (float)v[k][0], a0c);
                a1c = fmaf(p, (float)v[k][1], a1c);
                a2c = fmaf(p, (float)v[k][2], a2c);
                a3c = fmaf(p, (float)v[k][3], a3c);
                s += p;
            }
        }
    }
    a0c += __shfl_xor(a0c, 32, 64);
    a1c += __shfl_xor(a1c, 32, 64);
    a2c += __shfl_xor(a2c, 32, 64);
    a3c += __shfl_xor(a3c, 32, 64);
    s   += __shfl_xor(s, 32, 64);
    float ps = 0.f, pd = 0.f;
    if (half == 0) {
        float inv = 1.f / (s + 1e-16f);
        float4 bb = ((const float4*)b1)[m];
        float o0 = fmaxf(fmaf(a0c, inv, bb.x), 0.f);  // relu between layers
        float o1 = fmaxf(fmaf(a1c, inv, bb.y), 0.f);
        float o2 = fmaxf(fmaf(a2c, inv, bb.z), 0.f);
        float o3 = fmaxf(fmaf(a3c, inv, bb.w), 0.f);
        f16x4 o;
        o[0] = (_Float16)o0; o[1] = (_Float16)o1;
        o[2] = (_Float16)o2; o[3] = (_Float16)o3;
        ((f16x4*)out)[node * 32 + m] = o;
        float4 w2s = ((const float4*)wa2)[m];
        float4 w2d = ((const float4*)(wa2 + 128))[m];
        ps = o0 * w2s.x + o1 * w2s.y + o2 * w2s.z + o3 * w2s.w;
        pd = o0 * w2d.x + o1 * w2d.y + o2 * w2d.z + o3 * w2d.w;
    }
#pragma unroll
    for (int o = 1; o <= 16; o <<= 1) {
        ps += __shfl_xor(ps, o, 64);
        pd += __shfl_xor(pd, o, 64);
    }
    if (lane == 0) {
        asrc2[node] = ps;
        adst2[node] = pd;
    }
}

// layer 2: one wave per dst node, direct-col layout. lane = {eslot(3b), sub(3b)}.
// R16: 24-edge batches (3 groups in flight; 2 loop iters at mean degree 33).
__global__ __launch_bounds__(256) void agg2_kernel(const __half* __restrict__ h2bh,
                                                   const float* __restrict__ asrc,
                                                   const float* __restrict__ adst,
                                                   const int* __restrict__ row_ptr,
                                                   const unsigned short* __restrict__ col,
                                                   const float* __restrict__ b2,
                                                   float* __restrict__ out, int n) {
    int wave = threadIdx.x >> 6;
    int lane = threadIdx.x & 63;
    int node = blockIdx.x * 4 + wave;
    if (node >= n) return;
    int eslot = lane >> 3;         // 8 edge slots
    int sub = lane & 7;            // 8 x f16x8 chunks = 64 ch
    const char* __restrict__ h2c = (const char*)h2bh;
    unsigned coff = (unsigned)sub << 4;   // byte offset of lane's 16B chunk (<128)
    float ad = adst[node];
    int start = row_ptr[node], end = row_ptr[node + 1];
    int end1 = end - 1;
    float acc[8];
#pragma unroll
    for (int c = 0; c < 8; ++c) acc[c] = 0.f;
    float s = 0.f;
    for (int base = start; base < end; base += 24) {
        // issue phase: 3 edge-groups
        int iA = base + eslot;
        int iB = iA + 8;
        int iC = iA + 16;
        int sA = (int)col[min(iA, end1)];
        int sB = (int)col[min(iB, end1)];
        int sC = (int)col[min(iC, end1)];
        f16x8 vA = *(const f16x8*)(h2c + ((((unsigned)sA) << 7) | coff));
        f16x8 vB = *(const f16x8*)(h2c + ((((unsigned)sB) << 7) | coff));
        f16x8 vC = *(const f16x8*)(h2c + ((((unsigned)sC) << 7) | coff));
        float eA = asrc[sA] + ad;
        float eB = asrc[sB] + ad;
        float eC = asrc[sC] + ad;
        // consume phase
        eA = fmaxf(eA, LRELU_SLOPE * eA);
        eB = fmaxf(eB, LRELU_SLOPE * eB);
        eC = fmaxf(eC, LRELU_SLOPE * eC);
        float pA = (iA < end) ? __expf(eA) : 0.f;
        float pB = (iB < end) ? __expf(eB) : 0.f;
        float pC = (iC < end) ? __expf(eC) : 0.f;
#pragma unroll
        for (int c = 0; c < 8; ++c) acc[c] = fmaf(pA, (float)vA[c], acc[c]);
#pragma unroll
        for (int c = 0; c < 8; ++c) acc[c] = fmaf(pB, (float)vB[c], acc[c]);
#pragma unroll
        for (int c = 0; c < 8; ++c) acc[c] = fmaf(pC, (float)vC[c], acc[c]);
        s += pA + pB + pC;
    }
    // reduce across the 8 edge slots (strides 8..32); sub axis untouched
#pragma unroll
    for (int o = 8; o < 64; o <<= 1) {
#pragma unroll
        for (int c = 0; c < 8; ++c) acc[c] += __shfl_xor(acc[c], o, 64);
        s += __shfl_xor(s, o, 64);
    }
    if (lane < 8) {  // eslot == 0 lanes hold the 8 chunks
        float inv = 1.f / (s + 1e-16f);
        float4 bb0 = ((const float4*)b2)[sub * 2];
        float4 bb1 = ((const float4*)b2)[sub * 2 + 1];
        float4 o0, o1;
        o0.x = fmaf(acc[0], inv, bb0.x);
        o0.y = fmaf(acc[1], inv, bb0.y);
        o0.z = fmaf(acc[2], inv, bb0.z);
        o0.w = fmaf(acc[3], inv, bb0.w);
        o1.x = fmaf(acc[4], inv, bb1.x);
        o1.y = fmaf(acc[5], inv, bb1.y);
        o1.z = fmaf(acc[6], inv, bb1.z);
        o1.w = fmaf(acc[7], inv, bb1.w);
        ((float4*)(out + (size_t)node * 64))[sub * 2] = o0;
        ((float4*)(out + (size_t)node * 64))[sub * 2 + 1] = o1;
    }
}

// ---------------- launch ----------------

extern "C" void kernel_launch(void* const* d_in, const int* in_sizes, int n_in,
                              void* d_out, int out_size, void* d_ws, size_t ws_size,
                              hipStream_t stream) {
    const float* x      = (const float*)d_in[0];
    const int*   ei     = (const int*)d_in[1];
    const float* W1     = (const float*)d_in[2];
    const float* a_src1 = (const float*)d_in[3];
    const float* a_dst1 = (const float*)d_in[4];
    const float* b1     = (const float*)d_in[5];
    const float* W2     = (const float*)d_in[6];
    const float* a_src2 = (const float*)d_in[7];
    const float* a_dst2 = (const float*)d_in[8];
    const float* b2     = (const float*)d_in[9];
    float* out = (float*)d_out;

    const int N = in_sizes[0] / 128;
    const int E = in_sizes[1] / 2;
    const int total = E + N;
    const int nBuckets = (N + 255) >> 8;   // 196

    char* ws = (char*)d_ws;
    size_t off = 0;
    auto alloc = [&](size_t bytes) {
        void* p = ws + off;
        off += (bytes + 255) & ~(size_t)255;
        return p;
    };
    // Region A: records (CSR build), then h2in fp16 (agg1->gemm2).
    float* regionA = (float*)alloc((size_t)N * 128 * 4);
    __half* h1h   = (__half*)alloc((size_t)N * 128 * 2);
    __half* h2bh  = (__half*)alloc((size_t)N * 64 * 2);
    float* asrc1  = (float*)alloc((size_t)N * 4 * 4);
    float* adst1  = (float*)alloc((size_t)N * 4 * 4);
    float* asrc2  = (float*)alloc((size_t)N * 4);
    float* adst2  = (float*)alloc((size_t)N * 4);
    int*   row_ptr= (int*)alloc((size_t)(N + 1) * 4);
    int*   gfill  = (int*)alloc((size_t)nBuckets * 4);
    float* wa2    = (float*)alloc(256 * 4);
    unsigned short* col = (unsigned short*)alloc((size_t)total * 2);

    unsigned int* records = (unsigned int*)regionA;          // 13.1MB
    __half* h2in = (__half*)regionA;                         // after CSR build done
    (void)ws_size; (void)n_in; (void)out_size;

    const int* ei_src = ei;
    const int* ei_dst = ei + E;

    const int chunk = (E + NBLK - 1) / NBLK;   // 3125 <= SCAP
    const int G1B = (N + 63) / 64;     // 782
    const int ALB = (N + 255) / 256;   // 196

    hipMemsetAsync(gfill, 0, (size_t)nBuckets * 4, stream);

    // K1: scatter || gemm1 || alpha1 || wa2
    k1_kernel<<<NBLK + G1B + ALB + 1, 256, 0, stream>>>(
        ei_src, ei_dst, records, gfill,
        x, W1, h1h, a_src1, a_dst1, asrc1, adst1,
        W2, a_src2, a_dst2, wa2,
        E, chunk, N, G1B, ALB);

    csr_fused_kernel<<<nBuckets, 1024, 0, stream>>>(records, gfill, row_ptr, col, N, total);

    agg1_kernel<<<(N + 3) / 4, 256, 0, stream>>>(h1h, asrc1, adst1,
                                                 row_ptr, col, b1, wa2,
                                                 h2in, asrc2, adst2, N);

    gemm2_mfma_kernel<<<(N + 63) / 64, 256, 0, stream>>>(h2in, W2, h2bh, N);
    agg2_kernel<<<(N + 3) / 4, 256, 0, stream>>>(h2bh, asrc2, adst2,
                                                 row_ptr, col, b2, out, N);
}

// Round 8
// 222.658 us; speedup vs baseline: 1.7537x; 1.0056x over previous
//
#include <hip/hip_runtime.h>
#include <hip/hip_bf16.h>
#include <hip/hip_fp16.h>

// ---------------------------------------------------------------------------
// 2-layer GAT, N=50000, E=1.6M (+N self loops).
// R17 pipeline (6 dispatches):
//   memset(gfill) -> K1 [LDS-sorted scatter || gemm1-MFMA || alpha1 fp32 ||
//   wa2 build] -> csr_fused(1024thr, SRC-TILE-SORTED rows) -> agg1(+alpha2)
//   -> gemm2(pure) -> agg2(24-edge batches).
// Key facts carried forward:
//  - agg1 @57us/172MB: random-64B-line gathers on 12.8MB table, ~69% L2 miss.
//    R11 probe (3x MLP = +7%) killed latency theory; R12 channel-slicing
//    (3.8x worse) killed XCD-pinning. R17 lever: row order is semantically
//    free -> sort each row's edges by src-tile (8 x 8192 nodes = 2MB h1h
//    slices). Resident waves then walk tiles in loose phase-sync -> working
//    set ~1-3 tiles -> L2 hits. Same col[] ordering helps agg2 for free.
//  - csr_fused @1024thr was the R16 win (-16us). alphas as fp32 mini-GEMMs.
// ---------------------------------------------------------------------------

#define LRELU_SLOPE 0.2f
#define NBMAX 200        // max dst buckets (N <= 51200)
#define NBLK  512        // blocks in scatter role
#define BCAP  16384      // per-bucket record capacity (mean ~8163)
#define CAPIMG 16384     // csr_fused LDS image entries
#define SCAP  3328       // scatter stage capacity (chunk <= 3328)

typedef _Float16 f16x8 __attribute__((ext_vector_type(8)));
typedef _Float16 f16x4 __attribute__((ext_vector_type(4)));
typedef float f32x4 __attribute__((ext_vector_type(4)));

// ---------------- K1: scatter || gemm1 || alpha1 || wa2 ----------------
// Roles by blockIdx.x:
//   [0, NBLK)                : LDS counting-sort scatter of edge records
//   [NBLK, NBLK+G1B)         : gemm1 MFMA (X fp32 [n,128] @ W1 -> h1h fp16)
//   [NBLK+G1B, NBLK+G1B+ALB) : alpha1 = X @ [W1.a_src1 | W1.a_dst1] (fp32)
//   [NBLK+G1B+ALB]           : wa2 = [W2.a_src2 | W2.a_dst2] (256 floats)

__global__ __launch_bounds__(256) void k1_kernel(
    const int* __restrict__ ei_src, const int* __restrict__ ei_dst,
    unsigned int* __restrict__ records, int* __restrict__ gfill,
    const float* __restrict__ X, const float* __restrict__ W1,
    __half* __restrict__ h1h,
    const float* __restrict__ a_src1, const float* __restrict__ a_dst1,
    float* __restrict__ asrc1, float* __restrict__ adst1,
    const float* __restrict__ W2,
    const float* __restrict__ a_src2, const float* __restrict__ a_dst2,
    float* __restrict__ wa2,
    int E, int chunk, int N, int G1B, int ALB) {
    __shared__ __align__(16) char smem[34816];
    int t = threadIdx.x;
    int bid = blockIdx.x;

    if (bid < NBLK) {
        // ---------------- scatter role: LDS counting sort ----------------
        int* hist   = (int*)smem;            // [256] counts -> excl scan
        int* base_g = hist + 256;            // [256] global ticket base
        int* cur    = base_g + 256;          // [256] running fill
        int* sbuf   = cur + 256;             // [2][256] scan double-buffer
        unsigned int* ustage = (unsigned int*)(sbuf + 512);  // [SCAP]
        unsigned int* sstage = ustage + SCAP;                // [SCAP]

        hist[t] = 0;
        __syncthreads();
        int begin = bid * chunk;
        int endE = min(E, begin + chunk);
        int nE = endE - begin;
        for (int i = t; i < nE; i += 256) {
            int s = ei_src[begin + i], d = ei_dst[begin + i];
            unsigned int rec = (unsigned int)d | ((unsigned int)s << 16);
            ustage[i] = rec;
            atomicAdd(&hist[d >> 8], 1);
        }
        __syncthreads();
        int h = hist[t];
        if (t < NBMAX && h) base_g[t] = atomicAdd(&gfill[t], h);
        // exclusive scan of hist over 256 entries
        sbuf[t] = h;
        __syncthreads();
        int pi = 0;
#pragma unroll
        for (int off = 1; off < 256; off <<= 1) {
            int v = sbuf[pi * 256 + t];
            if (t >= off) v += sbuf[pi * 256 + t - off];
            sbuf[(pi ^ 1) * 256 + t] = v;
            __syncthreads();
            pi ^= 1;
        }
        int excl = sbuf[pi * 256 + t] - h;
        hist[t] = excl;   // repurpose hist as exclusive scan
        cur[t] = excl;
        __syncthreads();
        // sort into sstage
        for (int i = t; i < nE; i += 256) {
            unsigned int rec = ustage[i];
            int bkt = (rec & 0xFFFF) >> 8;
            int r = atomicAdd(&cur[bkt], 1);
            sstage[r] = rec;
        }
        __syncthreads();
        // coalesced flush: consecutive lanes write consecutive addresses
        // within each bucket run (avg run ~ 16 recs = 64B)
        for (int i = t; i < nE; i += 256) {
            unsigned int rec = sstage[i];
            int bkt = (rec & 0xFFFF) >> 8;
            int g = base_g[bkt] + (i - hist[bkt]);
            records[(size_t)bkt * BCAP + g] = rec;
        }
        return;
    }

    if (bid < NBLK + G1B) {
        // ---------------- gemm1 role (no alpha epilogue) ----------------
        constexpr int KP = 136;
        _Float16* wlds = (_Float16*)smem;  // wlds[n][k] = W1[k][n], 128xKP
        int gb = bid - NBLK;
        int wv = t >> 6, lane = t & 63;
        int quad = lane >> 4, m16 = lane & 15;
        for (int i = t; i < 4096; i += 256) {  // 128*128/4
            int k = i >> 5;
            int n0 = (i & 31) << 2;
            float4 v = *(const float4*)(W1 + k * 128 + n0);
            wlds[(n0 + 0) * KP + k] = (_Float16)v.x;
            wlds[(n0 + 1) * KP + k] = (_Float16)v.y;
            wlds[(n0 + 2) * KP + k] = (_Float16)v.z;
            wlds[(n0 + 3) * KP + k] = (_Float16)v.w;
        }
        __syncthreads();

        int row = gb * 64 + wv * 16 + m16;
        int rowC = min(row, N - 1);
        const float* xp = X + (size_t)rowC * 128;

        f32x4 acc[8];
#pragma unroll
        for (int nt = 0; nt < 8; ++nt) acc[nt] = (f32x4)0.f;

        for (int kt = 0; kt < 128; kt += 32) {
            float4 v0 = *(const float4*)(xp + kt + quad * 8);
            float4 v1 = *(const float4*)(xp + kt + quad * 8 + 4);
            f16x8 af;
            af[0] = (_Float16)v0.x; af[1] = (_Float16)v0.y;
            af[2] = (_Float16)v0.z; af[3] = (_Float16)v0.w;
            af[4] = (_Float16)v1.x; af[5] = (_Float16)v1.y;
            af[6] = (_Float16)v1.z; af[7] = (_Float16)v1.w;
#pragma unroll
            for (int nt = 0; nt < 8; ++nt) {
                f16x8 bf = *(const f16x8*)(&wlds[(nt * 16 + m16) * KP + kt + quad * 8]);
                acc[nt] = __builtin_amdgcn_mfma_f32_16x16x32_f16(af, bf, acc[nt], 0, 0, 0);
            }
        }

        int rowBaseW = gb * 64 + wv * 16;
#pragma unroll
        for (int r = 0; r < 4; ++r) {
            int orow = rowBaseW + quad * 4 + r;
            if (orow < N) {
#pragma unroll
                for (int nt = 0; nt < 8; ++nt)
                    h1h[(size_t)orow * 128 + nt * 16 + m16] = __float2half(acc[nt][r]);
            }
        }
        return;
    }

    int aid = bid - NBLK - G1B;
    if (aid < ALB) {
        // ---------------- alpha1 role: [N,128] @ [128,8] fp32 ----------------
        float* waL = (float*)smem;  // [8][128]
        {
            int k = t >> 1, grp = t & 1;
            const float* wrow = W1 + k * 128;
            const float* abase = grp ? a_dst1 : a_src1;
#pragma unroll
            for (int h = 0; h < 4; ++h) {
                const float* av = abase + h * 32;
                const float* wr = wrow + h * 32;
                float acc = 0.f;
                for (int c = 0; c < 32; ++c) acc += wr[c] * av[c];
                waL[(grp * 4 + h) * 128 + k] = acc;
            }
        }
        __syncthreads();
        int row = aid * 256 + t;
        if (row < N) {
            const float4* x4 = (const float4*)(X + (size_t)row * 128);
            float p[8];
#pragma unroll
            for (int o = 0; o < 8; ++o) p[o] = 0.f;
            for (int k4 = 0; k4 < 32; ++k4) {
                float4 xv = x4[k4];
#pragma unroll
                for (int o = 0; o < 8; ++o) {
                    float4 wv = ((const float4*)(waL + o * 128))[k4];
                    p[o] += xv.x * wv.x + xv.y * wv.y + xv.z * wv.z + xv.w * wv.w;
                }
            }
            float4 ps = {p[0], p[1], p[2], p[3]};
            float4 pd = {p[4], p[5], p[6], p[7]};
            ((float4*)asrc1)[row] = ps;
            ((float4*)adst1)[row] = pd;
        }
        return;
    }

    // ---------------- wa2 build block ----------------
    if (t < 128) {
        const float* wr = W2 + t * 64;
        float acc = 0.f;
        for (int c = 0; c < 64; ++c) acc += wr[c] * a_src2[c];
        wa2[t] = acc;
    } else {
        int k = t - 128;
        const float* wr = W2 + k * 64;
        float acc = 0.f;
        for (int c = 0; c < 64; ++c) acc += wr[c] * a_dst2[c];
        wa2[128 + k] = acc;
    }
}

// ---------------- CSR finalize: fused prefix + degree + scan + scatter ----
// R17: rows are SRC-TILE-SORTED — per (node, src>>13) counters; within each
// row, edges appear in ascending src-tile order (8 tiles x 8192 nodes).
// agg kernels then walk h-tables tile-by-tile in loose cross-wave phase sync.

__global__ __launch_bounds__(1024) void csr_fused_kernel(const unsigned int* __restrict__ records,
                                                         const int* __restrict__ gfill,
                                                         int* __restrict__ row_ptr,
                                                         unsigned short* __restrict__ col,
                                                         int N, int total) {
    __shared__ unsigned short img[CAPIMG];
    __shared__ int cnt2[256 * 8];   // per (node, src-tile) counts -> cursors
    __shared__ int sbuf[2][256];    // degree scan
    __shared__ int rbuf[4];
    int t = threadIdx.x, b = blockIdx.x;
    int bBase = b << 8;
    int bEnd = min(bBase + 256, N);
    int gi = bBase + t;
    int c = gfill[b];
    cnt2[t] = 0;
    cnt2[t + 1024] = 0;
    if (t < 256) {
        // inline prefix: rbase = sum_{i<b} gfill[i] + 256*b
        int pv = (t < b) ? gfill[t] : 0;
#pragma unroll
        for (int o = 1; o < 64; o <<= 1) pv += __shfl_xor(pv, o, 64);
        if ((t & 63) == 0) rbuf[t >> 6] = pv;
    }
    if (b == 0 && t == 0) row_ptr[N] = total;
    __syncthreads();
    const unsigned int* r = records + (size_t)b * BCAP;
    // count per (node, src-tile): rec = d | (s<<16); tile = s>>13 = rec>>29
    for (int i = t; i < c; i += 1024) {
        unsigned int rec = r[i];
        atomicAdd(&cnt2[((rec & 255) << 3) | (rec >> 29)], 1);
    }
    __syncthreads();
    int d = 0;
    if (t < 256) {
#pragma unroll
        for (int k = 0; k < 8; ++k) d += cnt2[(t << 3) | k];
        d += (gi < bEnd) ? 1 : 0;   // self loop
        sbuf[0][t] = d;
    }
    __syncthreads();
    int pi = 0;
#pragma unroll
    for (int off = 1; off < 256; off <<= 1) {
        if (t < 256) {
            int v = sbuf[pi][t];
            if (t >= off) v += sbuf[pi][t - off];
            sbuf[pi ^ 1][t] = v;
        }
        __syncthreads();
        pi ^= 1;
    }
    int rbase = rbuf[0] + rbuf[1] + rbuf[2] + rbuf[3] + (b << 8);
    int size = c + (bEnd - bBase);
    bool lds = (size <= CAPIMG);
    if (t < 256 && gi < bEnd) {
        int local = sbuf[pi][t] - d;   // exclusive prefix within bucket
        row_ptr[gi] = rbase + local;
        // in-place tile bases (slot 0 = self loop)
        int run = local + 1;
#pragma unroll
        for (int k = 0; k < 8; ++k) {
            int cc = cnt2[(t << 3) | k];
            cnt2[(t << 3) | k] = run;
            run += cc;
        }
        if (lds) img[local] = (unsigned short)gi;
        else col[rbase + local] = (unsigned short)gi;
    }
    __syncthreads();
    for (int i = t; i < c; i += 1024) {
        unsigned int rec = r[i];
        int idx2 = ((rec & 255) << 3) | (rec >> 29);
        unsigned short s = (unsigned short)(rec >> 16);
        int p = atomicAdd(&cnt2[idx2], 1);
        if (lds) img[p] = s;
        else col[rbase + p] = s;
    }
    __syncthreads();
    if (lds) {
        for (int i = t; i < size; i += 1024) col[rbase + i] = img[i];
    }
}

// ---------------- GEMM2: h2in fp16 [n,128] @ W2 [128,64] -> h2bh fp16 ----

__global__ __launch_bounds__(256) void gemm2_mfma_kernel(const __half* __restrict__ Xh,
                                                         const float* __restrict__ W,
                                                         __half* __restrict__ outh, int nrows) {
    constexpr int KP = 136;
    __shared__ _Float16 wlds[64 * KP];  // wlds[n][k] = W[k][n]
    int t = threadIdx.x;
    int wv = t >> 6, lane = t & 63;
    int quad = lane >> 4, m16 = lane & 15;
    for (int i = t; i < 2048; i += 256) {  // 128*64/4
        int k = i >> 4;
        int n0 = (i & 15) << 2;
        float4 v = *(const float4*)(W + k * 64 + n0);
        wlds[(n0 + 0) * KP + k] = (_Float16)v.x;
        wlds[(n0 + 1) * KP + k] = (_Float16)v.y;
        wlds[(n0 + 2) * KP + k] = (_Float16)v.z;
        wlds[(n0 + 3) * KP + k] = (_Float16)v.w;
    }
    __syncthreads();

    int row = blockIdx.x * 64 + wv * 16 + m16;
    int rowC = min(row, nrows - 1);
    const _Float16* xp = (const _Float16*)Xh + (size_t)rowC * 128;

    f32x4 acc[4];
#pragma unroll
    for (int nt = 0; nt < 4; ++nt) acc[nt] = (f32x4)0.f;

    for (int kt = 0; kt < 128; kt += 32) {
        f16x8 af = *(const f16x8*)(xp + kt + quad * 8);
#pragma unroll
        for (int nt = 0; nt < 4; ++nt) {
            f16x8 bf = *(const f16x8*)(&wlds[(nt * 16 + m16) * KP + kt + quad * 8]);
            acc[nt] = __builtin_amdgcn_mfma_f32_16x16x32_f16(af, bf, acc[nt], 0, 0, 0);
        }
    }

    int rowBaseW = blockIdx.x * 64 + wv * 16;
#pragma unroll
    for (int r = 0; r < 4; ++r) {
        int orow = rowBaseW + quad * 4 + r;
        if (orow < nrows) {
#pragma unroll
            for (int nt = 0; nt < 4; ++nt)
                outh[(size_t)orow * 64 + nt * 16 + m16] = __float2half(acc[nt][r]);
        }
    }
}

// ---------------- aggregation ----------------

// layer 1 (R11 form, at the random-line ceiling) + fused alpha2 epilogue.
__global__ __launch_bounds__(256) void agg1_kernel(const __half* __restrict__ h1h,
                                                   const float* __restrict__ asrc,
                                                   const float* __restrict__ adst,
                                                   const int* __restrict__ row_ptr,
                                                   const unsigned short* __restrict__ col,
                                                   const float* __restrict__ b1,
                                                   const float* __restrict__ wa2,
                                                   __half* __restrict__ out,
                                                   float* __restrict__ asrc2,
                                                   float* __restrict__ adst2, int n) {
    int wave = threadIdx.x >> 6;
    int lane = threadIdx.x & 63;
    int node = blockIdx.x * 4 + wave;
    if (node >= n) return;
    int half = lane >> 5;
    int m = lane & 31;             // f16x4 chunk index within 128-ch row
    int head = m >> 3;             // 4 heads x 8 chunks
    const char* __restrict__ h1c = (const char*)h1h;
    const char* __restrict__ asc = (const char*)asrc;
    unsigned moff = (unsigned)m << 3;    // byte offset of lane's 8B chunk (<256)
    unsigned aoff = (unsigned)head << 2; // byte offset into 16B asrc row
    float ad = adst[node * 4 + head];
    int start = row_ptr[node], end = row_ptr[node + 1];
    float a0c = 0.f, a1c = 0.f, a2c = 0.f, a3c = 0.f, s = 0.f;
    for (int base = start; base < end; base += 64) {
        int cnt = min(64, end - base);
        int idx = base + lane;
        int myS = (idx < end) ? (int)col[idx] : 0;
        for (int j = 0; j < cnt; j += 12) {
            // ---- issue phase: 6 row-gathers + 6 asrc gathers per lane ----
            int jj[6];
            int sv[6];
#pragma unroll
            for (int k = 0; k < 6; ++k) {
                jj[k] = j + 2 * k + half;          // >=64 wraps in shfl; guarded below
                sv[k] = __shfl(myS, jj[k], 64);
            }
            f16x4 v[6];
            float as[6];
#pragma unroll
            for (int k = 0; k < 6; ++k) {
                v[k]  = *(const f16x4*)(h1c + ((((unsigned)sv[k]) << 8) | moff));
                as[k] = *(const float*)(asc + ((((unsigned)sv[k]) << 4) | aoff));
            }
            // ---- consume phase ----
#pragma unroll
            for (int k = 0; k < 6; ++k) {
                float e = as[k] + ad;
                e = fmaxf(e, LRELU_SLOPE * e);
                float p = (jj[k] < cnt) ? __expf(e) : 0.f;
                a0c = fmaf(p, (float)v[k][0], a0c);
                a1c = fmaf(p, (float)v[k][1], a1c);
                a2c = fmaf(p, (float)v[k][2], a2c);
                a3c = fmaf(p, (float)v[k][3], a3c);
                s += p;
            }
        }
    }
    a0c += __shfl_xor(a0c, 32, 64);
    a1c += __shfl_xor(a1c, 32, 64);
    a2c += __shfl_xor(a2c, 32, 64);
    a3c += __shfl_xor(a3c, 32, 64);
    s   += __shfl_xor(s, 32, 64);
    float ps = 0.f, pd = 0.f;
    if (half == 0) {
        float inv = 1.f / (s + 1e-16f);
        float4 bb = ((const float4*)b1)[m];
        float o0 = fmaxf(fmaf(a0c, inv, bb.x), 0.f);  // relu between layers
        float o1 = fmaxf(fmaf(a1c, inv, bb.y), 0.f);
        float o2 = fmaxf(fmaf(a2c, inv, bb.z), 0.f);
        float o3 = fmaxf(fmaf(a3c, inv, bb.w), 0.f);
        f16x4 o;
        o[0] = (_Float16)o0; o[1] = (_Float16)o1;
        o[2] = (_Float16)o2; o[3] = (_Float16)o3;
        ((f16x4*)out)[node * 32 + m] = o;
        float4 w2s = ((const float4*)wa2)[m];
        float4 w2d = ((const float4*)(wa2 + 128))[m];
        ps = o0 * w2s.x + o1 * w2s.y + o2 * w2s.z + o3 * w2s.w;
        pd = o0 * w2d.x + o1 * w2d.y + o2 * w2d.z + o3 * w2d.w;
    }
#pragma unroll
    for (int o = 1; o <= 16; o <<= 1) {
        ps += __shfl_xor(ps, o, 64);
        pd += __shfl_xor(pd, o, 64);
    }
    if (lane == 0) {
        asrc2[node] = ps;
        adst2[node] = pd;
    }
}

// layer 2: one wave per dst node, direct-col layout. lane = {eslot(3b), sub(3b)}.
// 24-edge batches (3 groups in flight; 2 loop iters at mean degree 33).
__global__ __launch_bounds__(256) void agg2_kernel(const __half* __restrict__ h2bh,
                                                   const float* __restrict__ asrc,
                                                   const float* __restrict__ adst,
                                                   const int* __restrict__ row_ptr,
                                                   const unsigned short* __restrict__ col,
                                                   const float* __restrict__ b2,
                                                   float* __restrict__ out, int n) {
    int wave = threadIdx.x >> 6;
    int lane = threadIdx.x & 63;
    int node = blockIdx.x * 4 + wave;
    if (node >= n) return;
    int eslot = lane >> 3;         // 8 edge slots
    int sub = lane & 7;            // 8 x f16x8 chunks = 64 ch
    const char* __restrict__ h2c = (const char*)h2bh;
    unsigned coff = (unsigned)sub << 4;   // byte offset of lane's 16B chunk (<128)
    float ad = adst[node];
    int start = row_ptr[node], end = row_ptr[node + 1];
    int end1 = end - 1;
    float acc[8];
#pragma unroll
    for (int c = 0; c < 8; ++c) acc[c] = 0.f;
    float s = 0.f;
    for (int base = start; base < end; base += 24) {
        // issue phase: 3 edge-groups
        int iA = base + eslot;
        int iB = iA + 8;
        int iC = iA + 16;
        int sA = (int)col[min(iA, end1)];
        int sB = (int)col[min(iB, end1)];
        int sC = (int)col[min(iC, end1)];
        f16x8 vA = *(const f16x8*)(h2c + ((((unsigned)sA) << 7) | coff));
        f16x8 vB = *(const f16x8*)(h2c + ((((unsigned)sB) << 7) | coff));
        f16x8 vC = *(const f16x8*)(h2c + ((((unsigned)sC) << 7) | coff));
        float eA = asrc[sA] + ad;
        float eB = asrc[sB] + ad;
        float eC = asrc[sC] + ad;
        // consume phase
        eA = fmaxf(eA, LRELU_SLOPE * eA);
        eB = fmaxf(eB, LRELU_SLOPE * eB);
        eC = fmaxf(eC, LRELU_SLOPE * eC);
        float pA = (iA < end) ? __expf(eA) : 0.f;
        float pB = (iB < end) ? __expf(eB) : 0.f;
        float pC = (iC < end) ? __expf(eC) : 0.f;
#pragma unroll
        for (int c = 0; c < 8; ++c) acc[c] = fmaf(pA, (float)vA[c], acc[c]);
#pragma unroll
        for (int c = 0; c < 8; ++c) acc[c] = fmaf(pB, (float)vB[c], acc[c]);
#pragma unroll
        for (int c = 0; c < 8; ++c) acc[c] = fmaf(pC, (float)vC[c], acc[c]);
        s += pA + pB + pC;
    }
    // reduce across the 8 edge slots (strides 8..32); sub axis untouched
#pragma unroll
    for (int o = 8; o < 64; o <<= 1) {
#pragma unroll
        for (int c = 0; c < 8; ++c) acc[c] += __shfl_xor(acc[c], o, 64);
        s += __shfl_xor(s, o, 64);
    }
    if (lane < 8) {  // eslot == 0 lanes hold the 8 chunks
        float inv = 1.f / (s + 1e-16f);
        float4 bb0 = ((const float4*)b2)[sub * 2];
        float4 bb1 = ((const float4*)b2)[sub * 2 + 1];
        float4 o0, o1;
        o0.x = fmaf(acc[0], inv, bb0.x);
        o0.y = fmaf(acc[1], inv, bb0.y);
        o0.z = fmaf(acc[2], inv, bb0.z);
        o0.w = fmaf(acc[3], inv, bb0.w);
        o1.x = fmaf(acc[4], inv, bb1.x);
        o1.y = fmaf(acc[5], inv, bb1.y);
        o1.z = fmaf(acc[6], inv, bb1.z);
        o1.w = fmaf(acc[7], inv, bb1.w);
        ((float4*)(out + (size_t)node * 64))[sub * 2] = o0;
        ((float4*)(out + (size_t)node * 64))[sub * 2 + 1] = o1;
    }
}

// ---------------- launch ----------------

extern "C" void kernel_launch(void* const* d_in, const int* in_sizes, int n_in,
                              void* d_out, int out_size, void* d_ws, size_t ws_size,
                              hipStream_t stream) {
    const float* x      = (const float*)d_in[0];
    const int*   ei     = (const int*)d_in[1];
    const float* W1     = (const float*)d_in[2];
    const float* a_src1 = (const float*)d_in[3];
    const float* a_dst1 = (const float*)d_in[4];
    const float* b1     = (const float*)d_in[5];
    const float* W2     = (const float*)d_in[6];
    const float* a_src2 = (const float*)d_in[7];
    const float* a_dst2 = (const float*)d_in[8];
    const float* b2     = (const float*)d_in[9];
    float* out = (float*)d_out;

    const int N = in_sizes[0] / 128;
    const int E = in_sizes[1] / 2;
    const int total = E + N;
    const int nBuckets = (N + 255) >> 8;   // 196

    char* ws = (char*)d_ws;
    size_t off = 0;
    auto alloc = [&](size_t bytes) {
        void* p = ws + off;
        off += (bytes + 255) & ~(size_t)255;
        return p;
    };
    // Region A: records (CSR build), then h2in fp16 (agg1->gemm2).
    float* regionA = (float*)alloc((size_t)N * 128 * 4);
    __half* h1h   = (__half*)alloc((size_t)N * 128 * 2);
    __half* h2bh  = (__half*)alloc((size_t)N * 64 * 2);
    float* asrc1  = (float*)alloc((size_t)N * 4 * 4);
    float* adst1  = (float*)alloc((size_t)N * 4 * 4);
    float* asrc2  = (float*)alloc((size_t)N * 4);
    float* adst2  = (float*)alloc((size_t)N * 4);
    int*   row_ptr= (int*)alloc((size_t)(N + 1) * 4);
    int*   gfill  = (int*)alloc((size_t)nBuckets * 4);
    float* wa2    = (float*)alloc(256 * 4);
    unsigned short* col = (unsigned short*)alloc((size_t)total * 2);

    unsigned int* records = (unsigned int*)regionA;          // 13.1MB
    __half* h2in = (__half*)regionA;                         // after CSR build done
    (void)ws_size; (void)n_in; (void)out_size;

    const int* ei_src = ei;
    const int* ei_dst = ei + E;

    const int chunk = (E + NBLK - 1) / NBLK;   // 3125 <= SCAP
    const int G1B = (N + 63) / 64;     // 782
    const int ALB = (N + 255) / 256;   // 196

    hipMemsetAsync(gfill, 0, (size_t)nBuckets * 4, stream);

    // K1: scatter || gemm1 || alpha1 || wa2
    k1_kernel<<<NBLK + G1B + ALB + 1, 256, 0, stream>>>(
        ei_src, ei_dst, records, gfill,
        x, W1, h1h, a_src1, a_dst1, asrc1, adst1,
        W2, a_src2, a_dst2, wa2,
        E, chunk, N, G1B, ALB);

    csr_fused_kernel<<<nBuckets, 1024, 0, stream>>>(records, gfill, row_ptr, col, N, total);

    agg1_kernel<<<(N + 3) / 4, 256, 0, stream>>>(h1h, asrc1, adst1,
                                                 row_ptr, col, b1, wa2,
                                                 h2in, asrc2, adst2, N);

    gemm2_mfma_kernel<<<(N + 63) / 64, 256, 0, stream>>>(h2in, W2, h2bh, N);
    agg2_kernel<<<(N + 3) / 4, 256, 0, stream>>>(h2bh, asrc2, adst2,
                                                 row_ptr, col, b2, out, N);
}